// Round 2
// baseline (336.920 us; speedup 1.0000x reference)
//
#include <hip/hip_runtime.h>
#include <math.h>

// Problem constants (from reference): B=4, N=L=5, C=64, H=100, W=252
#define BB 4
#define NN 5
#define CC 64
#define HH 100
#define WW 252
#define HW (HH * WW)

// out[b*N+i, c, h, w] = max_j bilinear_sample(x[b*N+j, c], affine(T[b,i,j]) @ (gx,gy,1))
__global__ __launch_bounds__(256) void where2comm_fuse_kernel(
    const float* __restrict__ x,   // (B*N, C, H, W)
    const float* __restrict__ T,   // (B, L, L, 4, 4)
    float* __restrict__ out)       // (B*N, C, H, W)
{
    const int tid = blockIdx.x * blockDim.x + threadIdx.x;
    const int total = BB * NN * HW;
    if (tid >= total) return;

    const int w  = tid % WW;
    const int t2 = tid / WW;
    const int h  = t2 % HH;
    const int bi = t2 / HH;
    const int b  = bi / NN;
    const int i  = bi % NN;

    // base grid: gx = linspace(-1,1,W)[w], gy = linspace(-1,1,H)[h]
    const float gx = -1.0f + 2.0f * (float)w / (float)(WW - 1);
    const float gy = -1.0f + 2.0f * (float)h / (float)(HH - 1);

    float acc[CC];
#pragma unroll
    for (int c = 0; c < CC; ++c) acc[c] = -INFINITY;

    // scale constants: 2/(DOWNSAMPLE_RATE*DISCRETE_RATIO*W) = 2.5/W, same for H
    const float sHW = (float)HH / (float)WW;
    const float sWH = (float)WW / (float)HH;
    const float sW  = 2.5f / (float)WW;
    const float sH  = 2.5f / (float)HH;

    for (int j = 0; j < NN; ++j) {
        const float* Tm = T + ((size_t)(b * NN + i) * NN + j) * 16;
        // M = rows {0,1} x cols {0,1,3} of T, elementwise * scale
        const float m00 = Tm[0];
        const float m01 = Tm[1] * sHW;
        const float m02 = Tm[3] * sW;
        const float m10 = Tm[4] * sWH;
        const float m11 = Tm[5];
        const float m12 = Tm[7] * sH;

        const float cx = __builtin_fmaf(m00, gx, __builtin_fmaf(m01, gy, m02));
        const float cy = __builtin_fmaf(m10, gx, __builtin_fmaf(m11, gy, m12));

        // to source pixel coords (align_corners=True)
        const float ix = (cx + 1.0f) * (0.5f * (float)(WW - 1));
        const float iy = (cy + 1.0f) * (0.5f * (float)(HH - 1));

        const float x0f = floorf(ix);
        const float y0f = floorf(iy);
        const int x0 = (int)x0f;
        const int y0 = (int)y0f;
        const int x1 = x0 + 1;
        const int y1 = y0 + 1;

        const float wx1 = ix - x0f;
        const float wy1 = iy - y0f;
        const float wx0 = 1.0f - wx1;
        const float wy0 = 1.0f - wy1;

        // validity folded into weights (invalid tap contributes 0, like ref)
        const float v00 = (x0 >= 0 && x0 < WW && y0 >= 0 && y0 < HH) ? 1.0f : 0.0f;
        const float v01 = (x1 >= 0 && x1 < WW && y0 >= 0 && y0 < HH) ? 1.0f : 0.0f;
        const float v10 = (x0 >= 0 && x0 < WW && y1 >= 0 && y1 < HH) ? 1.0f : 0.0f;
        const float v11 = (x1 >= 0 && x1 < WW && y1 >= 0 && y1 < HH) ? 1.0f : 0.0f;

        const float w00 = wy0 * wx0 * v00;
        const float w01 = wy0 * wx1 * v01;
        const float w10 = wy1 * wx0 * v10;
        const float w11 = wy1 * wx1 * v11;

        const int x0c = min(max(x0, 0), WW - 1);
        const int x1c = min(max(x1, 0), WW - 1);
        const int y0c = min(max(y0, 0), HH - 1);
        const int y1c = min(max(y1, 0), HH - 1);

        const int o00 = y0c * WW + x0c;
        const int o01 = y0c * WW + x1c;
        const int o10 = y1c * WW + x0c;
        const int o11 = y1c * WW + x1c;

        const float* p = x + (size_t)(b * NN + j) * CC * HW;

#pragma unroll
        for (int c = 0; c < CC; ++c) {
            const float* pc = p + (size_t)c * HW;
            const float s = __builtin_fmaf(w00, pc[o00],
                            __builtin_fmaf(w01, pc[o01],
                            __builtin_fmaf(w10, pc[o10],
                                           w11 * pc[o11])));
            acc[c] = fmaxf(acc[c], s);
        }
    }

    float* op = out + (size_t)bi * CC * HW + h * WW + w;
#pragma unroll
    for (int c = 0; c < CC; ++c) op[(size_t)c * HW] = acc[c];
}

extern "C" void kernel_launch(void* const* d_in, const int* in_sizes, int n_in,
                              void* d_out, int out_size, void* d_ws, size_t ws_size,
                              hipStream_t stream) {
    const float* x = (const float*)d_in[0];
    // d_in[1] = confidence_map (unused), d_in[2] = record_len (unused)
    const float* T = (const float*)d_in[3];
    float* out = (float*)d_out;

    const int total = BB * NN * HW;           // 504000 pixels
    const int block = 256;
    const int grid = (total + block - 1) / block;
    where2comm_fuse_kernel<<<grid, block, 0, stream>>>(x, T, out);
}

// Round 3
// 296.326 us; speedup vs baseline: 1.1370x; 1.1370x over previous
//
#include <hip/hip_runtime.h>
#include <math.h>

// Problem constants (from reference): B=4, N=L=5, C=64, H=100, W=252
#define BB 4
#define NN 5
#define CC 64
#define HH 100
#define WW 252
#define HW (HH * WW)
#define CG 8                 // channels per thread
#define NCG (CC / CG)        // 8 channel-groups

// out[b*N+i, c, h, w] = max_j bilinear_sample(x[b*N+j, c], affine(T[b,i,j]) @ (gx,gy,1))
// One thread = one output pixel x 8 channels. 32 independent gathers in
// flight per j-step -> latency hiding via MLP instead of occupancy alone.
__global__ __launch_bounds__(256, 4) void where2comm_fuse_kernel(
    const float* __restrict__ x,   // (B*N, C, H, W)
    const float* __restrict__ T,   // (B, L, L, 4, 4)
    float* __restrict__ out)       // (B*N, C, H, W)
{
    const int tid = blockIdx.x * blockDim.x + threadIdx.x;
    const int total = BB * NN * HW * NCG;
    if (tid >= total) return;

    // w fastest (coalescing), then h (adjacent blocks share source lines),
    // then (b,i), channel-group slowest (L3 absorbs the 8x re-walk of x).
    const int w   = tid % WW;
    int t2        = tid / WW;
    const int h   = t2 % HH;
    t2           /= HH;
    const int bi  = t2 % (BB * NN);
    const int cg  = t2 / (BB * NN);
    const int b   = bi / NN;
    const int i   = bi % NN;

    const float gx = -1.0f + 2.0f * (float)w / (float)(WW - 1);
    const float gy = -1.0f + 2.0f * (float)h / (float)(HH - 1);

    float acc[CG];
#pragma unroll
    for (int c = 0; c < CG; ++c) acc[c] = -INFINITY;

    const float sHW = (float)HH / (float)WW;
    const float sWH = (float)WW / (float)HH;
    const float sW  = 2.5f / (float)WW;
    const float sH  = 2.5f / (float)HH;

    for (int j = 0; j < NN; ++j) {
        const float* Tm = T + ((size_t)(b * NN + i) * NN + j) * 16;
        const float m00 = Tm[0];
        const float m01 = Tm[1] * sHW;
        const float m02 = Tm[3] * sW;
        const float m10 = Tm[4] * sWH;
        const float m11 = Tm[5];
        const float m12 = Tm[7] * sH;

        const float cx = __builtin_fmaf(m00, gx, __builtin_fmaf(m01, gy, m02));
        const float cy = __builtin_fmaf(m10, gx, __builtin_fmaf(m11, gy, m12));

        const float ix = (cx + 1.0f) * (0.5f * (float)(WW - 1));
        const float iy = (cy + 1.0f) * (0.5f * (float)(HH - 1));

        const float x0f = floorf(ix);
        const float y0f = floorf(iy);
        const int x0 = (int)x0f;
        const int y0 = (int)y0f;
        const int x1 = x0 + 1;
        const int y1 = y0 + 1;

        const float wx1 = ix - x0f;
        const float wy1 = iy - y0f;
        const float wx0 = 1.0f - wx1;
        const float wy0 = 1.0f - wy1;

        const float v00 = (x0 >= 0 && x0 < WW && y0 >= 0 && y0 < HH) ? 1.0f : 0.0f;
        const float v01 = (x1 >= 0 && x1 < WW && y0 >= 0 && y0 < HH) ? 1.0f : 0.0f;
        const float v10 = (x0 >= 0 && x0 < WW && y1 >= 0 && y1 < HH) ? 1.0f : 0.0f;
        const float v11 = (x1 >= 0 && x1 < WW && y1 >= 0 && y1 < HH) ? 1.0f : 0.0f;

        const float w00 = wy0 * wx0 * v00;
        const float w01 = wy0 * wx1 * v01;
        const float w10 = wy1 * wx0 * v10;
        const float w11 = wy1 * wx1 * v11;

        const int x0c = min(max(x0, 0), WW - 1);
        const int x1c = min(max(x1, 0), WW - 1);
        const int y0c = min(max(y0, 0), HH - 1);
        const int y1c = min(max(y1, 0), HH - 1);

        const int o00 = y0c * WW + x0c;
        const int o01 = y0c * WW + x1c;
        const int o10 = y1c * WW + x0c;
        const int o11 = y1c * WW + x1c;

        const float* p = x + ((size_t)(b * NN + j) * CC + cg * CG) * HW;

        // Issue all 32 gathers before any arithmetic -> deep MLP.
        float t00[CG], t01[CG], t10[CG], t11[CG];
#pragma unroll
        for (int c = 0; c < CG; ++c) {
            const float* pc = p + (size_t)c * HW;
            t00[c] = pc[o00];
            t01[c] = pc[o01];
            t10[c] = pc[o10];
            t11[c] = pc[o11];
        }
#pragma unroll
        for (int c = 0; c < CG; ++c) {
            const float s = __builtin_fmaf(w00, t00[c],
                            __builtin_fmaf(w01, t01[c],
                            __builtin_fmaf(w10, t10[c],
                                           w11 * t11[c])));
            acc[c] = fmaxf(acc[c], s);
        }
    }

    float* op = out + ((size_t)bi * CC + cg * CG) * HW + h * WW + w;
#pragma unroll
    for (int c = 0; c < CG; ++c) op[(size_t)c * HW] = acc[c];
}

extern "C" void kernel_launch(void* const* d_in, const int* in_sizes, int n_in,
                              void* d_out, int out_size, void* d_ws, size_t ws_size,
                              hipStream_t stream) {
    const float* x = (const float*)d_in[0];
    // d_in[1] = confidence_map (unused), d_in[2] = record_len (unused)
    const float* T = (const float*)d_in[3];
    float* out = (float*)d_out;

    const int total = BB * NN * HW * NCG;     // 4,032,000 threads
    const int block = 256;
    const int grid = (total + block - 1) / block;   // 15750 blocks
    where2comm_fuse_kernel<<<grid, block, 0, stream>>>(x, T, out);
}

// Round 4
// 284.416 us; speedup vs baseline: 1.1846x; 1.0419x over previous
//
#include <hip/hip_runtime.h>
#include <math.h>

// Problem constants (from reference): B=4, N=L=5, C=64, H=100, W=252
#define BB 4
#define NN 5
#define CC 64
#define HH 100
#define WW 252
#define HW (HH * WW)
#define CG 16                // channels per thread
#define NCG (CC / CG)        // 4 channel-groups

// out[b*N+i, c, h, w] = max_j bilinear_sample(x[b*N+j, c], affine(T[b,i,j]) @ (gx,gy,1))
// One thread = one output pixel x 16 channels. All 64 gathers of a j-step are
// issued before any consumption (sched_barrier fence) -> 64 wave-loads in
// flight per wave -> gather-transaction throughput instead of latency.
__global__ __launch_bounds__(256, 4) void where2comm_fuse_kernel(
    const float* __restrict__ x,   // (B*N, C, H, W)
    const float* __restrict__ T,   // (B, L, L, 4, 4)
    float* __restrict__ out)       // (B*N, C, H, W)
{
    const int tid = blockIdx.x * blockDim.x + threadIdx.x;
    const int total = BB * NN * HW * NCG;
    if (tid >= total) return;

    // w fastest (coalescing), then h, then (b,i), channel-group slowest.
    const int w   = tid % WW;
    int t2        = tid / WW;
    const int h   = t2 % HH;
    t2           /= HH;
    const int bi  = t2 % (BB * NN);
    const int cg  = t2 / (BB * NN);
    const int b   = bi / NN;
    const int i   = bi % NN;

    const float gx = -1.0f + 2.0f * (float)w / (float)(WW - 1);
    const float gy = -1.0f + 2.0f * (float)h / (float)(HH - 1);

    float acc[CG];
#pragma unroll
    for (int c = 0; c < CG; ++c) acc[c] = -INFINITY;

    const float sHW = (float)HH / (float)WW;
    const float sWH = (float)WW / (float)HH;
    const float sW  = 2.5f / (float)WW;
    const float sH  = 2.5f / (float)HH;

    for (int j = 0; j < NN; ++j) {
        const float* Tm = T + ((size_t)(b * NN + i) * NN + j) * 16;
        const float m00 = Tm[0];
        const float m01 = Tm[1] * sHW;
        const float m02 = Tm[3] * sW;
        const float m10 = Tm[4] * sWH;
        const float m11 = Tm[5];
        const float m12 = Tm[7] * sH;

        const float cx = __builtin_fmaf(m00, gx, __builtin_fmaf(m01, gy, m02));
        const float cy = __builtin_fmaf(m10, gx, __builtin_fmaf(m11, gy, m12));

        const float ix = (cx + 1.0f) * (0.5f * (float)(WW - 1));
        const float iy = (cy + 1.0f) * (0.5f * (float)(HH - 1));

        const float x0f = floorf(ix);
        const float y0f = floorf(iy);
        const int x0 = (int)x0f;
        const int y0 = (int)y0f;
        const int x1 = x0 + 1;
        const int y1 = y0 + 1;

        const float wx1 = ix - x0f;
        const float wy1 = iy - y0f;
        const float wx0 = 1.0f - wx1;
        const float wy0 = 1.0f - wy1;

        const float v00 = (x0 >= 0 && x0 < WW && y0 >= 0 && y0 < HH) ? 1.0f : 0.0f;
        const float v01 = (x1 >= 0 && x1 < WW && y0 >= 0 && y0 < HH) ? 1.0f : 0.0f;
        const float v10 = (x0 >= 0 && x0 < WW && y1 >= 0 && y1 < HH) ? 1.0f : 0.0f;
        const float v11 = (x1 >= 0 && x1 < WW && y1 >= 0 && y1 < HH) ? 1.0f : 0.0f;

        const float w00 = wy0 * wx0 * v00;
        const float w01 = wy0 * wx1 * v01;
        const float w10 = wy1 * wx0 * v10;
        const float w11 = wy1 * wx1 * v11;

        const int x0c = min(max(x0, 0), WW - 1);
        const int x1c = min(max(x1, 0), WW - 1);
        const int y0c = min(max(y0, 0), HH - 1);
        const int y1c = min(max(y1, 0), HH - 1);

        const int o00 = y0c * WW + x0c;
        const int o01 = y0c * WW + x1c;
        const int o10 = y1c * WW + x0c;
        const int o11 = y1c * WW + x1c;

        const float* p = x + ((size_t)(b * NN + j) * CC + cg * CG) * HW;

        // Phase 1: issue all 64 independent gathers.
        float t00[CG], t01[CG], t10[CG], t11[CG];
#pragma unroll
        for (int c = 0; c < CG; ++c) {
            const float* pc = p + (size_t)c * HW;
            t00[c] = pc[o00];
            t01[c] = pc[o01];
            t10[c] = pc[o10];
            t11[c] = pc[o11];
        }
        // Hard scheduling fence: nothing moves across -> all 64 results must
        // be live simultaneously -> deep MLP instead of 4-8-load batches.
        __builtin_amdgcn_sched_barrier(0);

        // Phase 2: consume.
#pragma unroll
        for (int c = 0; c < CG; ++c) {
            const float s = __builtin_fmaf(w00, t00[c],
                            __builtin_fmaf(w01, t01[c],
                            __builtin_fmaf(w10, t10[c],
                                           w11 * t11[c])));
            acc[c] = fmaxf(acc[c], s);
        }
    }

    float* op = out + ((size_t)bi * CC + cg * CG) * HW + h * WW + w;
#pragma unroll
    for (int c = 0; c < CG; ++c) op[(size_t)c * HW] = acc[c];
}

extern "C" void kernel_launch(void* const* d_in, const int* in_sizes, int n_in,
                              void* d_out, int out_size, void* d_ws, size_t ws_size,
                              hipStream_t stream) {
    const float* x = (const float*)d_in[0];
    // d_in[1] = confidence_map (unused), d_in[2] = record_len (unused)
    const float* T = (const float*)d_in[3];
    float* out = (float*)d_out;

    const int total = BB * NN * HW * NCG;     // 2,016,000 threads
    const int block = 256;
    const int grid = (total + block - 1) / block;
    where2comm_fuse_kernel<<<grid, block, 0, stream>>>(x, T, out);
}

// Round 6
// 218.537 us; speedup vs baseline: 1.5417x; 1.3015x over previous
//
#include <hip/hip_runtime.h>
#include <math.h>

// Problem constants: B=4, N=L=5, C=64, H=100, W=252
#define BB 4
#define NN 5
#define CC 64
#define HH 100
#define WW 252
#define HW (HH * WW)
#define TILE_W 64
#define NTW ((WW + TILE_W - 1) / TILE_W)   // 4 tiles per row
#define CSTR 9                              // coord LDS stride (conflict-free)

// ---------- pass 1: transpose x (BN,C,H,W) -> xt (BN,H,W,C) ----------
__global__ __launch_bounds__(256) void transpose_chw_hwc(
    const float* __restrict__ x, float* __restrict__ xt)
{
    __shared__ float tile[CC][TILE_W + 1];
    const int blk = blockIdx.x;
    const int wt  = blk % NTW;
    const int h   = (blk / NTW) % HH;
    const int bn  = blk / (NTW * HH);
    const int w0  = wt * TILE_W;

    const int lane = threadIdx.x & 63;
    const int sub  = threadIdx.x >> 6;    // 0..3

#pragma unroll
    for (int it = 0; it < 16; ++it) {     // read coalesced along w
        const int c = sub + 4 * it;
        const int w = w0 + lane;
        if (w < WW)
            tile[c][lane] = x[((size_t)(bn * CC + c) * HH + h) * WW + w];
    }
    __syncthreads();
#pragma unroll
    for (int it = 0; it < 16; ++it) {     // write coalesced along c
        const int p = sub + 4 * it;
        const int w = w0 + p;
        if (w < WW)
            xt[(((size_t)bn * HH + h) * WW + w) * CC + lane] = tile[lane][p];
    }
}

// ---------- pass 2: gather with lane=channel, write out coalesced ----------
__global__ __launch_bounds__(256) void fuse_gather(
    const float* __restrict__ xt,   // (BN, H, W, C)
    const float* __restrict__ T,    // (B, L, L, 4, 4)
    float* __restrict__ out)        // (BN, C, H, W)
{
    __shared__ float coord[NN][TILE_W][CSTR];   // per (j, pixel): 4 offsets + 4 weights
    __shared__ float tile[TILE_W][CC + 1];      // per (pixel, channel) result

    const int blk = blockIdx.x;
    const int wt  = blk % NTW;
    const int h   = (blk / NTW) % HH;
    const int bi  = blk / (NTW * HH);
    const int b   = bi / NN;
    const int i   = bi % NN;
    const int w0  = wt * TILE_W;

    const int lane = threadIdx.x & 63;
    const int wv   = threadIdx.x >> 6;   // 0..3

    // ---- phase 0: lane = pixel; waves split the j's. All-lane-parallel coord math.
    {
        const int w  = w0 + lane;
        const float gx = -1.0f + 2.0f * (float)w / (float)(WW - 1);
        const float gy = -1.0f + 2.0f * (float)h / (float)(HH - 1);
        const float sHW = (float)HH / (float)WW;
        const float sWH = (float)WW / (float)HH;
        const float sW  = 2.5f / (float)WW;
        const float sH  = 2.5f / (float)HH;

        for (int jj = wv; jj < NN; jj += 4) {
            const float* Tm = T + ((size_t)(b * NN + i) * NN + jj) * 16;
            const float m00 = Tm[0];
            const float m01 = Tm[1] * sHW;
            const float m02 = Tm[3] * sW;
            const float m10 = Tm[4] * sWH;
            const float m11 = Tm[5];
            const float m12 = Tm[7] * sH;

            const float cx = __builtin_fmaf(m00, gx, __builtin_fmaf(m01, gy, m02));
            const float cy = __builtin_fmaf(m10, gx, __builtin_fmaf(m11, gy, m12));
            const float ix = (cx + 1.0f) * (0.5f * (float)(WW - 1));
            const float iy = (cy + 1.0f) * (0.5f * (float)(HH - 1));

            const float x0f = floorf(ix);
            const float y0f = floorf(iy);
            const int x0 = (int)x0f, y0 = (int)y0f;
            const int x1 = x0 + 1,  y1 = y0 + 1;

            const float wx1 = ix - x0f, wy1 = iy - y0f;
            const float wx0 = 1.0f - wx1, wy0 = 1.0f - wy1;

            const float v00 = (x0 >= 0 && x0 < WW && y0 >= 0 && y0 < HH) ? 1.0f : 0.0f;
            const float v01 = (x1 >= 0 && x1 < WW && y0 >= 0 && y0 < HH) ? 1.0f : 0.0f;
            const float v10 = (x0 >= 0 && x0 < WW && y1 >= 0 && y1 < HH) ? 1.0f : 0.0f;
            const float v11 = (x1 >= 0 && x1 < WW && y1 >= 0 && y1 < HH) ? 1.0f : 0.0f;

            const int x0c = min(max(x0, 0), WW - 1);
            const int x1c = min(max(x1, 0), WW - 1);
            const int y0c = min(max(y0, 0), HH - 1);
            const int y1c = min(max(y1, 0), HH - 1);

            float* cd = coord[jj][lane];
            cd[0] = __int_as_float(y0c * WW + x0c);
            cd[1] = __int_as_float(y0c * WW + x1c);
            cd[2] = __int_as_float(y1c * WW + x0c);
            cd[3] = __int_as_float(y1c * WW + x1c);
            cd[4] = wy0 * wx0 * v00;
            cd[5] = wy0 * wx1 * v01;
            cd[6] = wy1 * wx0 * v10;
            cd[7] = wy1 * wx1 * v11;
        }
    }
    __syncthreads();

    // ---- phase A: wave wv owns pixels p = wv+4k; lane = channel. Each tap is one
    // aligned 256B vector load (scalar base via readfirstlane + lane*4).
#pragma unroll 4
    for (int k = 0; k < 16; ++k) {
        const int p = wv + 4 * k;          // wave-uniform
        if (w0 + p < WW) {
            float acc = -INFINITY;
#pragma unroll
            for (int j = 0; j < NN; ++j) {
                const float* cd = coord[j][p];
                const int o00 = __builtin_amdgcn_readfirstlane(__float_as_int(cd[0]));
                const int o01 = __builtin_amdgcn_readfirstlane(__float_as_int(cd[1]));
                const int o10 = __builtin_amdgcn_readfirstlane(__float_as_int(cd[2]));
                const int o11 = __builtin_amdgcn_readfirstlane(__float_as_int(cd[3]));
                const float w00 = cd[4], w01 = cd[5], w10 = cd[6], w11 = cd[7];

                const float* pj = xt + (size_t)(b * NN + j) * HW * CC;
                const float v00 = pj[(size_t)o00 * CC + lane];
                const float v01 = pj[(size_t)o01 * CC + lane];
                const float v10 = pj[(size_t)o10 * CC + lane];
                const float v11 = pj[(size_t)o11 * CC + lane];

                const float s = __builtin_fmaf(w00, v00,
                                __builtin_fmaf(w01, v01,
                                __builtin_fmaf(w10, v10,
                                               w11 * v11)));
                acc = fmaxf(acc, s);
            }
            tile[p][lane] = acc;
        }
    }
    __syncthreads();

    // ---- phase B: lane = w-offset, coalesced store to (bi, c, h, w)
#pragma unroll
    for (int it = 0; it < 16; ++it) {
        const int cc = wv + 4 * it;
        const int w  = w0 + lane;
        if (w < WW)
            out[((size_t)bi * CC + cc) * HW + h * WW + w] = tile[lane][cc];
    }
}

// ---------- fallback (round-4 kernel) if workspace is too small ----------
#define CG 16
#define NCG (CC / CG)
__global__ __launch_bounds__(256, 4) void where2comm_fuse_fallback(
    const float* __restrict__ x, const float* __restrict__ T,
    float* __restrict__ out)
{
    const int tid = blockIdx.x * blockDim.x + threadIdx.x;
    const int total = BB * NN * HW * NCG;
    if (tid >= total) return;
    const int w = tid % WW;
    int t2 = tid / WW;
    const int h = t2 % HH;
    t2 /= HH;
    const int bi = t2 % (BB * NN);
    const int cg = t2 / (BB * NN);
    const int b = bi / NN, i = bi % NN;
    const float gx = -1.0f + 2.0f * (float)w / (float)(WW - 1);
    const float gy = -1.0f + 2.0f * (float)h / (float)(HH - 1);
    float acc[CG];
#pragma unroll
    for (int c = 0; c < CG; ++c) acc[c] = -INFINITY;
    const float sHW = (float)HH / (float)WW, sWH = (float)WW / (float)HH;
    const float sW = 2.5f / (float)WW, sH = 2.5f / (float)HH;
    for (int j = 0; j < NN; ++j) {
        const float* Tm = T + ((size_t)(b * NN + i) * NN + j) * 16;
        const float m00 = Tm[0], m01 = Tm[1] * sHW, m02 = Tm[3] * sW;
        const float m10 = Tm[4] * sWH, m11 = Tm[5], m12 = Tm[7] * sH;
        const float cx = __builtin_fmaf(m00, gx, __builtin_fmaf(m01, gy, m02));
        const float cy = __builtin_fmaf(m10, gx, __builtin_fmaf(m11, gy, m12));
        const float ix = (cx + 1.0f) * (0.5f * (float)(WW - 1));
        const float iy = (cy + 1.0f) * (0.5f * (float)(HH - 1));
        const float x0f = floorf(ix), y0f = floorf(iy);
        const int x0 = (int)x0f, y0 = (int)y0f, x1 = x0 + 1, y1 = y0 + 1;
        const float wx1 = ix - x0f, wy1 = iy - y0f;
        const float wx0 = 1.0f - wx1, wy0 = 1.0f - wy1;
        const float v00 = (x0 >= 0 && x0 < WW && y0 >= 0 && y0 < HH) ? 1.0f : 0.0f;
        const float v01 = (x1 >= 0 && x1 < WW && y0 >= 0 && y0 < HH) ? 1.0f : 0.0f;
        const float v10 = (x0 >= 0 && x0 < WW && y1 >= 0 && y1 < HH) ? 1.0f : 0.0f;
        const float v11 = (x1 >= 0 && x1 < WW && y1 >= 0 && y1 < HH) ? 1.0f : 0.0f;
        const float w00 = wy0 * wx0 * v00, w01 = wy0 * wx1 * v01;
        const float w10 = wy1 * wx0 * v10, w11 = wy1 * wx1 * v11;
        const int x0c = min(max(x0, 0), WW - 1), x1c = min(max(x1, 0), WW - 1);
        const int y0c = min(max(y0, 0), HH - 1), y1c = min(max(y1, 0), HH - 1);
        const int o00 = y0c * WW + x0c, o01 = y0c * WW + x1c;
        const int o10 = y1c * WW + x0c, o11 = y1c * WW + x1c;
        const float* p = x + ((size_t)(b * NN + j) * CC + cg * CG) * HW;
        float t00[CG], t01[CG], t10[CG], t11[CG];
#pragma unroll
        for (int c = 0; c < CG; ++c) {
            const float* pc = p + (size_t)c * HW;
            t00[c] = pc[o00]; t01[c] = pc[o01]; t10[c] = pc[o10]; t11[c] = pc[o11];
        }
#pragma unroll
        for (int c = 0; c < CG; ++c) {
            const float s = __builtin_fmaf(w00, t00[c], __builtin_fmaf(w01, t01[c],
                            __builtin_fmaf(w10, t10[c], w11 * t11[c])));
            acc[c] = fmaxf(acc[c], s);
        }
    }
    float* op = out + ((size_t)bi * CC + cg * CG) * HW + h * WW + w;
#pragma unroll
    for (int c = 0; c < CG; ++c) op[(size_t)c * HW] = acc[c];
}

extern "C" void kernel_launch(void* const* d_in, const int* in_sizes, int n_in,
                              void* d_out, int out_size, void* d_ws, size_t ws_size,
                              hipStream_t stream) {
    const float* x = (const float*)d_in[0];
    const float* T = (const float*)d_in[3];
    float* out = (float*)d_out;

    const size_t xt_bytes = (size_t)BB * NN * HH * WW * CC * sizeof(float); // 129 MB
    if (ws_size >= xt_bytes) {
        float* xt = (float*)d_ws;
        const int grid1 = BB * NN * HH * NTW;   // 8000
        transpose_chw_hwc<<<grid1, 256, 0, stream>>>(x, xt);
        const int grid2 = BB * NN * HH * NTW;   // 8000
        fuse_gather<<<grid2, 256, 0, stream>>>(xt, T, out);
    } else {
        const int total = BB * NN * HW * NCG;
        where2comm_fuse_fallback<<<(total + 255) / 256, 256, 0, stream>>>(x, T, out);
    }
}

// Round 7
// 168.322 us; speedup vs baseline: 2.0016x; 1.2983x over previous
//
#include <hip/hip_runtime.h>
#include <math.h>

// Problem constants: B=4, N=L=5, C=64, H=100, W=252
#define BB 4
#define NN 5
#define CC 64
#define HH 100
#define WW 252
#define HW (HH * WW)
#define TILE_W 64
#define NTW ((WW + TILE_W - 1) / TILE_W)   // 4 tiles per row
#define CSTR 9                              // coord LDS stride (conflict-free)
#define NXCD 8

// ---------- pass 1: transpose x (BN,C,H,W) -> xt (BN,H,W,C) ----------
__global__ __launch_bounds__(256) void transpose_chw_hwc(
    const float* __restrict__ x, float* __restrict__ xt)
{
    __shared__ float tile[CC][TILE_W + 1];
    const int blk = blockIdx.x;
    const int wt  = blk % NTW;
    const int h   = (blk / NTW) % HH;
    const int bn  = blk / (NTW * HH);
    const int w0  = wt * TILE_W;

    const int lane = threadIdx.x & 63;
    const int sub  = threadIdx.x >> 6;    // 0..3

#pragma unroll
    for (int it = 0; it < 16; ++it) {     // read coalesced along w
        const int c = sub + 4 * it;
        const int w = w0 + lane;
        if (w < WW)
            tile[c][lane] = x[((size_t)(bn * CC + c) * HH + h) * WW + w];
    }
    __syncthreads();
#pragma unroll
    for (int it = 0; it < 16; ++it) {     // write coalesced along c
        const int p = sub + 4 * it;
        const int w = w0 + p;
        if (w < WW)
            xt[(((size_t)bn * HH + h) * WW + w) * CC + lane] = tile[lane][p];
    }
}

// ---------- pass 2: float4 gather, lane = (pixel-group, channel-quad) ----------
__global__ __launch_bounds__(256) void fuse_gather(
    const float* __restrict__ xt,   // (BN, H, W, C)
    const float* __restrict__ T,    // (B, L, L, 4, 4)
    float* __restrict__ out)        // (BN, C, H, W)
{
    __shared__ float coord[NN][TILE_W][CSTR];   // per (j, pixel): 4 offsets + 4 weights
    __shared__ float tile[TILE_W][CC + 1];      // per (pixel, channel) result

    // XCD chunked swizzle (bijective: 8000 % 8 == 0): keeps adjacent-h blocks
    // (which reuse the same xt rows) on the same XCD's L2.
    const int cpx = gridDim.x / NXCD;
    const int blk = (blockIdx.x % NXCD) * cpx + blockIdx.x / NXCD;

    const int wt  = blk % NTW;
    const int h   = (blk / NTW) % HH;
    const int bi  = blk / (NTW * HH);
    const int b   = bi / NN;
    const int i   = bi % NN;
    const int w0  = wt * TILE_W;

    const int lane = threadIdx.x & 63;
    const int wv   = threadIdx.x >> 6;   // 0..3

    // ---- phase 0: lane = pixel; waves split the j's.
    {
        const int w  = w0 + lane;
        const float gx = -1.0f + 2.0f * (float)w / (float)(WW - 1);
        const float gy = -1.0f + 2.0f * (float)h / (float)(HH - 1);
        const float sHW = (float)HH / (float)WW;
        const float sWH = (float)WW / (float)HH;
        const float sW  = 2.5f / (float)WW;
        const float sH  = 2.5f / (float)HH;

        for (int jj = wv; jj < NN; jj += 4) {
            const float* Tm = T + ((size_t)(b * NN + i) * NN + jj) * 16;
            const float m00 = Tm[0];
            const float m01 = Tm[1] * sHW;
            const float m02 = Tm[3] * sW;
            const float m10 = Tm[4] * sWH;
            const float m11 = Tm[5];
            const float m12 = Tm[7] * sH;

            const float cx = __builtin_fmaf(m00, gx, __builtin_fmaf(m01, gy, m02));
            const float cy = __builtin_fmaf(m10, gx, __builtin_fmaf(m11, gy, m12));
            const float ix = (cx + 1.0f) * (0.5f * (float)(WW - 1));
            const float iy = (cy + 1.0f) * (0.5f * (float)(HH - 1));

            const float x0f = floorf(ix);
            const float y0f = floorf(iy);
            const int x0 = (int)x0f, y0 = (int)y0f;
            const int x1 = x0 + 1,  y1 = y0 + 1;

            const float wx1 = ix - x0f, wy1 = iy - y0f;
            const float wx0 = 1.0f - wx1, wy0 = 1.0f - wy1;

            const float v00 = (x0 >= 0 && x0 < WW && y0 >= 0 && y0 < HH) ? 1.0f : 0.0f;
            const float v01 = (x1 >= 0 && x1 < WW && y0 >= 0 && y0 < HH) ? 1.0f : 0.0f;
            const float v10 = (x0 >= 0 && x0 < WW && y1 >= 0 && y1 < HH) ? 1.0f : 0.0f;
            const float v11 = (x1 >= 0 && x1 < WW && y1 >= 0 && y1 < HH) ? 1.0f : 0.0f;

            const int x0c = min(max(x0, 0), WW - 1);
            const int x1c = min(max(x1, 0), WW - 1);
            const int y0c = min(max(y0, 0), HH - 1);
            const int y1c = min(max(y1, 0), HH - 1);

            float* cd = coord[jj][lane];
            cd[0] = __int_as_float(y0c * WW + x0c);
            cd[1] = __int_as_float(y0c * WW + x1c);
            cd[2] = __int_as_float(y1c * WW + x0c);
            cd[3] = __int_as_float(y1c * WW + x1c);
            cd[4] = wy0 * wx0 * v00;
            cd[5] = wy0 * wx1 * v01;
            cd[6] = wy1 * wx0 * v10;
            cd[7] = wy1 * wx1 * v11;
        }
    }
    __syncthreads();

    // ---- phase A: each wave handles 16 pixels as 4 iters x 4 pixel-groups.
    // lane = (group g = lane>>4 -> pixel, channel-quad = (lane&15)*4).
    // Each tap: global_load_dwordx4; the wave's 4 groups read 4 consecutive
    // 256B pixel-segments -> typically one contiguous 1KB span.
    {
        const int g   = lane >> 4;
        const int ch4 = (lane & 15) * 4;

#pragma unroll
        for (int it = 0; it < 4; ++it) {
            const int p = wv * 16 + it * 4 + g;
            const bool valid = (w0 + p < WW);
            float ax = -INFINITY, ay = -INFINITY, az = -INFINITY, aw = -INFINITY;
#pragma unroll
            for (int j = 0; j < NN; ++j) {
                const float* cd = coord[j][p];
                const int o00 = __float_as_int(cd[0]);
                const int o01 = __float_as_int(cd[1]);
                const int o10 = __float_as_int(cd[2]);
                const int o11 = __float_as_int(cd[3]);
                const float w00 = cd[4], w01 = cd[5], w10 = cd[6], w11 = cd[7];

                const float* pj = xt + (size_t)(b * NN + j) * HW * CC;
                const float4 t00 = *(const float4*)(pj + (size_t)o00 * CC + ch4);
                const float4 t01 = *(const float4*)(pj + (size_t)o01 * CC + ch4);
                const float4 t10 = *(const float4*)(pj + (size_t)o10 * CC + ch4);
                const float4 t11 = *(const float4*)(pj + (size_t)o11 * CC + ch4);

                float s;
                s = __builtin_fmaf(w00, t00.x, __builtin_fmaf(w01, t01.x,
                    __builtin_fmaf(w10, t10.x, w11 * t11.x)));
                ax = fmaxf(ax, s);
                s = __builtin_fmaf(w00, t00.y, __builtin_fmaf(w01, t01.y,
                    __builtin_fmaf(w10, t10.y, w11 * t11.y)));
                ay = fmaxf(ay, s);
                s = __builtin_fmaf(w00, t00.z, __builtin_fmaf(w01, t01.z,
                    __builtin_fmaf(w10, t10.z, w11 * t11.z)));
                az = fmaxf(az, s);
                s = __builtin_fmaf(w00, t00.w, __builtin_fmaf(w01, t01.w,
                    __builtin_fmaf(w10, t10.w, w11 * t11.w)));
                aw = fmaxf(aw, s);
            }
            if (valid) {
                float* tp = &tile[p][ch4];
                tp[0] = ax; tp[1] = ay; tp[2] = az; tp[3] = aw;
            }
        }
    }
    __syncthreads();

    // ---- phase B: lane = w-offset, coalesced store to (bi, c, h, w)
#pragma unroll
    for (int it = 0; it < 16; ++it) {
        const int cc = wv + 4 * it;
        const int w  = w0 + lane;
        if (w < WW)
            out[((size_t)bi * CC + cc) * HW + h * WW + w] = tile[lane][cc];
    }
}

// ---------- fallback (round-4 kernel) if workspace is too small ----------
#define CG 16
#define NCG (CC / CG)
__global__ __launch_bounds__(256, 4) void where2comm_fuse_fallback(
    const float* __restrict__ x, const float* __restrict__ T,
    float* __restrict__ out)
{
    const int tid = blockIdx.x * blockDim.x + threadIdx.x;
    const int total = BB * NN * HW * NCG;
    if (tid >= total) return;
    const int w = tid % WW;
    int t2 = tid / WW;
    const int h = t2 % HH;
    t2 /= HH;
    const int bi = t2 % (BB * NN);
    const int cg = t2 / (BB * NN);
    const int b = bi / NN, i = bi % NN;
    const float gx = -1.0f + 2.0f * (float)w / (float)(WW - 1);
    const float gy = -1.0f + 2.0f * (float)h / (float)(HH - 1);
    float acc[CG];
#pragma unroll
    for (int c = 0; c < CG; ++c) acc[c] = -INFINITY;
    const float sHW = (float)HH / (float)WW, sWH = (float)WW / (float)HH;
    const float sW = 2.5f / (float)WW, sH = 2.5f / (float)HH;
    for (int j = 0; j < NN; ++j) {
        const float* Tm = T + ((size_t)(b * NN + i) * NN + j) * 16;
        const float m00 = Tm[0], m01 = Tm[1] * sHW, m02 = Tm[3] * sW;
        const float m10 = Tm[4] * sWH, m11 = Tm[5], m12 = Tm[7] * sH;
        const float cx = __builtin_fmaf(m00, gx, __builtin_fmaf(m01, gy, m02));
        const float cy = __builtin_fmaf(m10, gx, __builtin_fmaf(m11, gy, m12));
        const float ix = (cx + 1.0f) * (0.5f * (float)(WW - 1));
        const float iy = (cy + 1.0f) * (0.5f * (float)(HH - 1));
        const float x0f = floorf(ix), y0f = floorf(iy);
        const int x0 = (int)x0f, y0 = (int)y0f, x1 = x0 + 1, y1 = y0 + 1;
        const float wx1 = ix - x0f, wy1 = iy - y0f;
        const float wx0 = 1.0f - wx1, wy0 = 1.0f - wy1;
        const float v00 = (x0 >= 0 && x0 < WW && y0 >= 0 && y0 < HH) ? 1.0f : 0.0f;
        const float v01 = (x1 >= 0 && x1 < WW && y0 >= 0 && y0 < HH) ? 1.0f : 0.0f;
        const float v10 = (x0 >= 0 && x0 < WW && y1 >= 0 && y1 < HH) ? 1.0f : 0.0f;
        const float v11 = (x1 >= 0 && x1 < WW && y1 >= 0 && y1 < HH) ? 1.0f : 0.0f;
        const float w00 = wy0 * wx0 * v00, w01 = wy0 * wx1 * v01;
        const float w10 = wy1 * wx0 * v10, w11 = wy1 * wx1 * v11;
        const int x0c = min(max(x0, 0), WW - 1), x1c = min(max(x1, 0), WW - 1);
        const int y0c = min(max(y0, 0), HH - 1), y1c = min(max(y1, 0), HH - 1);
        const int o00 = y0c * WW + x0c, o01 = y0c * WW + x1c;
        const int o10 = y1c * WW + x0c, o11 = y1c * WW + x1c;
        const float* p = x + ((size_t)(b * NN + j) * CC + cg * CG) * HW;
        float t00[CG], t01[CG], t10[CG], t11[CG];
#pragma unroll
        for (int c = 0; c < CG; ++c) {
            const float* pc = p + (size_t)c * HW;
            t00[c] = pc[o00]; t01[c] = pc[o01]; t10[c] = pc[o10]; t11[c] = pc[o11];
        }
#pragma unroll
        for (int c = 0; c < CG; ++c) {
            const float s = __builtin_fmaf(w00, t00[c], __builtin_fmaf(w01, t01[c],
                            __builtin_fmaf(w10, t10[c], w11 * t11[c])));
            acc[c] = fmaxf(acc[c], s);
        }
    }
    float* op = out + ((size_t)bi * CC + cg * CG) * HW + h * WW + w;
#pragma unroll
    for (int c = 0; c < CG; ++c) op[(size_t)c * HW] = acc[c];
}

extern "C" void kernel_launch(void* const* d_in, const int* in_sizes, int n_in,
                              void* d_out, int out_size, void* d_ws, size_t ws_size,
                              hipStream_t stream) {
    const float* x = (const float*)d_in[0];
    const float* T = (const float*)d_in[3];
    float* out = (float*)d_out;

    const size_t xt_bytes = (size_t)BB * NN * HH * WW * CC * sizeof(float); // 129 MB
    if (ws_size >= xt_bytes) {
        float* xt = (float*)d_ws;
        const int grid1 = BB * NN * HH * NTW;   // 8000
        transpose_chw_hwc<<<grid1, 256, 0, stream>>>(x, xt);
        const int grid2 = BB * NN * HH * NTW;   // 8000
        fuse_gather<<<grid2, 256, 0, stream>>>(xt, T, out);
    } else {
        const int total = BB * NN * HW * NCG;
        where2comm_fuse_fallback<<<(total + 255) / 256, 256, 0, stream>>>(x, T, out);
    }
}

// Round 8
// 167.650 us; speedup vs baseline: 2.0097x; 1.0040x over previous
//
#include <hip/hip_runtime.h>
#include <math.h>

// Problem constants: B=4, N=L=5, C=64, H=100, W=252
#define BB 4
#define NN 5
#define CC 64
#define HH 100
#define WW 252
#define HW (HH * WW)
#define TILE_W 64
#define NTW ((WW + TILE_W - 1) / TILE_W)   // 4 tiles per row
#define CSTR 9                              // coord LDS stride (conflict-free)
#define NXCD 8

// ---------- pass 1: transpose x (BN,C,H,W) -> xt (BN,H,W,C) ----------
__global__ __launch_bounds__(256) void transpose_chw_hwc(
    const float* __restrict__ x, float* __restrict__ xt)
{
    __shared__ float tile[CC][TILE_W + 1];
    const int blk = blockIdx.x;
    const int wt  = blk % NTW;
    const int h   = (blk / NTW) % HH;
    const int bn  = blk / (NTW * HH);
    const int w0  = wt * TILE_W;

    const int lane = threadIdx.x & 63;
    const int sub  = threadIdx.x >> 6;    // 0..3

#pragma unroll
    for (int it = 0; it < 16; ++it) {     // read coalesced along w
        const int c = sub + 4 * it;
        const int w = w0 + lane;
        if (w < WW)
            tile[c][lane] = x[((size_t)(bn * CC + c) * HH + h) * WW + w];
    }
    __syncthreads();
#pragma unroll
    for (int it = 0; it < 16; ++it) {     // write coalesced along c
        const int p = sub + 4 * it;
        const int w = w0 + p;
        if (w < WW)
            xt[(((size_t)bn * HH + h) * WW + w) * CC + lane] = tile[lane][p];
    }
}

// ---------- pass 2: float4 gather, 512 threads / 8 waves per block ----------
// Occupancy-first: 28.2KB LDS + 512thr -> 4 blocks x 8 waves = 32 waves/CU
// potential (wave-cap bound), ~3x the round-7 resident waves. TLP hides the
// gather latency the compiler's shallow load batching (VGPR~52) won't.
__global__ __launch_bounds__(512) void fuse_gather(
    const float* __restrict__ xt,   // (BN, H, W, C)
    const float* __restrict__ T,    // (B, L, L, 4, 4)
    float* __restrict__ out)        // (BN, C, H, W)
{
    __shared__ float coord[NN][TILE_W][CSTR];   // per (j, pixel): 4 offsets + 4 weights
    __shared__ float tile[TILE_W][CC + 1];      // per (pixel, channel) result

    // XCD chunked swizzle (bijective: 8000 % 8 == 0)
    const int cpx = gridDim.x / NXCD;
    const int blk = (blockIdx.x % NXCD) * cpx + blockIdx.x / NXCD;

    const int wt  = blk % NTW;
    const int h   = (blk / NTW) % HH;
    const int bi  = blk / (NTW * HH);
    const int b   = bi / NN;
    const int i   = bi % NN;
    const int w0  = wt * TILE_W;

    const int lane = threadIdx.x & 63;
    const int wv   = threadIdx.x >> 6;   // 0..7

    // ---- phase 0: waves 0..4 each compute one j's coords; lane = pixel.
    if (wv < NN) {
        const int jj = wv;
        const int w  = w0 + lane;
        const float gx = -1.0f + 2.0f * (float)w / (float)(WW - 1);
        const float gy = -1.0f + 2.0f * (float)h / (float)(HH - 1);
        const float sHW = (float)HH / (float)WW;
        const float sWH = (float)WW / (float)HH;
        const float sW  = 2.5f / (float)WW;
        const float sH  = 2.5f / (float)HH;

        const float* Tm = T + ((size_t)(b * NN + i) * NN + jj) * 16;
        const float m00 = Tm[0];
        const float m01 = Tm[1] * sHW;
        const float m02 = Tm[3] * sW;
        const float m10 = Tm[4] * sWH;
        const float m11 = Tm[5];
        const float m12 = Tm[7] * sH;

        const float cx = __builtin_fmaf(m00, gx, __builtin_fmaf(m01, gy, m02));
        const float cy = __builtin_fmaf(m10, gx, __builtin_fmaf(m11, gy, m12));
        const float ix = (cx + 1.0f) * (0.5f * (float)(WW - 1));
        const float iy = (cy + 1.0f) * (0.5f * (float)(HH - 1));

        const float x0f = floorf(ix);
        const float y0f = floorf(iy);
        const int x0 = (int)x0f, y0 = (int)y0f;
        const int x1 = x0 + 1,  y1 = y0 + 1;

        const float wx1 = ix - x0f, wy1 = iy - y0f;
        const float wx0 = 1.0f - wx1, wy0 = 1.0f - wy1;

        const float v00 = (x0 >= 0 && x0 < WW && y0 >= 0 && y0 < HH) ? 1.0f : 0.0f;
        const float v01 = (x1 >= 0 && x1 < WW && y0 >= 0 && y0 < HH) ? 1.0f : 0.0f;
        const float v10 = (x0 >= 0 && x0 < WW && y1 >= 0 && y1 < HH) ? 1.0f : 0.0f;
        const float v11 = (x1 >= 0 && x1 < WW && y1 >= 0 && y1 < HH) ? 1.0f : 0.0f;

        const int x0c = min(max(x0, 0), WW - 1);
        const int x1c = min(max(x1, 0), WW - 1);
        const int y0c = min(max(y0, 0), HH - 1);
        const int y1c = min(max(y1, 0), HH - 1);

        float* cd = coord[jj][lane];
        cd[0] = __int_as_float(y0c * WW + x0c);
        cd[1] = __int_as_float(y0c * WW + x1c);
        cd[2] = __int_as_float(y1c * WW + x0c);
        cd[3] = __int_as_float(y1c * WW + x1c);
        cd[4] = wy0 * wx0 * v00;
        cd[5] = wy0 * wx1 * v01;
        cd[6] = wy1 * wx0 * v10;
        cd[7] = wy1 * wx1 * v11;
    }
    __syncthreads();

    // ---- phase A: wave wv owns pixels wv*8 .. wv*8+7 (2 iters x 4 groups).
    // lane = (group g = lane>>4 -> pixel, channel-quad = (lane&15)*4).
    {
        const int g   = lane >> 4;
        const int ch4 = (lane & 15) * 4;

#pragma unroll
        for (int it = 0; it < 2; ++it) {
            const int p = wv * 8 + it * 4 + g;
            const bool valid = (w0 + p < WW);
            float ax = -INFINITY, ay = -INFINITY, az = -INFINITY, aw = -INFINITY;
#pragma unroll
            for (int j = 0; j < NN; ++j) {
                const float* cd = coord[j][p];
                const int o00 = __float_as_int(cd[0]);
                const int o01 = __float_as_int(cd[1]);
                const int o10 = __float_as_int(cd[2]);
                const int o11 = __float_as_int(cd[3]);
                const float w00 = cd[4], w01 = cd[5], w10 = cd[6], w11 = cd[7];

                const float* pj = xt + (size_t)(b * NN + j) * HW * CC;
                const float4 t00 = *(const float4*)(pj + (size_t)o00 * CC + ch4);
                const float4 t01 = *(const float4*)(pj + (size_t)o01 * CC + ch4);
                const float4 t10 = *(const float4*)(pj + (size_t)o10 * CC + ch4);
                const float4 t11 = *(const float4*)(pj + (size_t)o11 * CC + ch4);

                float s;
                s = __builtin_fmaf(w00, t00.x, __builtin_fmaf(w01, t01.x,
                    __builtin_fmaf(w10, t10.x, w11 * t11.x)));
                ax = fmaxf(ax, s);
                s = __builtin_fmaf(w00, t00.y, __builtin_fmaf(w01, t01.y,
                    __builtin_fmaf(w10, t10.y, w11 * t11.y)));
                ay = fmaxf(ay, s);
                s = __builtin_fmaf(w00, t00.z, __builtin_fmaf(w01, t01.z,
                    __builtin_fmaf(w10, t10.z, w11 * t11.z)));
                az = fmaxf(az, s);
                s = __builtin_fmaf(w00, t00.w, __builtin_fmaf(w01, t01.w,
                    __builtin_fmaf(w10, t10.w, w11 * t11.w)));
                aw = fmaxf(aw, s);
            }
            if (valid) {
                float* tp = &tile[p][ch4];
                tp[0] = ax; tp[1] = ay; tp[2] = az; tp[3] = aw;
            }
        }
    }
    __syncthreads();

    // ---- phase B: float4 stores along w. unit = (c, w-quad); 2 units/thread.
#pragma unroll
    for (int rep = 0; rep < 2; ++rep) {
        const int unit = threadIdx.x + 512 * rep;   // 0..1023
        const int q = unit & 15;                    // w-quad
        const int c = unit >> 4;                    // 0..63
        const int w = w0 + 4 * q;
        if (w < WW) {                               // tiles are multiples of 4 wide
            float4 v;
            v.x = tile[4 * q + 0][c];
            v.y = tile[4 * q + 1][c];
            v.z = tile[4 * q + 2][c];
            v.w = tile[4 * q + 3][c];
            *(float4*)(out + ((size_t)bi * CC + c) * HW + h * WW + w) = v;
        }
    }
}

// ---------- fallback (round-4 kernel) if workspace is too small ----------
#define CG 16
#define NCG (CC / CG)
__global__ __launch_bounds__(256, 4) void where2comm_fuse_fallback(
    const float* __restrict__ x, const float* __restrict__ T,
    float* __restrict__ out)
{
    const int tid = blockIdx.x * blockDim.x + threadIdx.x;
    const int total = BB * NN * HW * NCG;
    if (tid >= total) return;
    const int w = tid % WW;
    int t2 = tid / WW;
    const int h = t2 % HH;
    t2 /= HH;
    const int bi = t2 % (BB * NN);
    const int cg = t2 / (BB * NN);
    const int b = bi / NN, i = bi % NN;
    const float gx = -1.0f + 2.0f * (float)w / (float)(WW - 1);
    const float gy = -1.0f + 2.0f * (float)h / (float)(HH - 1);
    float acc[CG];
#pragma unroll
    for (int c = 0; c < CG; ++c) acc[c] = -INFINITY;
    const float sHW = (float)HH / (float)WW, sWH = (float)WW / (float)HH;
    const float sW = 2.5f / (float)WW, sH = 2.5f / (float)HH;
    for (int j = 0; j < NN; ++j) {
        const float* Tm = T + ((size_t)(b * NN + i) * NN + j) * 16;
        const float m00 = Tm[0], m01 = Tm[1] * sHW, m02 = Tm[3] * sW;
        const float m10 = Tm[4] * sWH, m11 = Tm[5], m12 = Tm[7] * sH;
        const float cx = __builtin_fmaf(m00, gx, __builtin_fmaf(m01, gy, m02));
        const float cy = __builtin_fmaf(m10, gx, __builtin_fmaf(m11, gy, m12));
        const float ix = (cx + 1.0f) * (0.5f * (float)(WW - 1));
        const float iy = (cy + 1.0f) * (0.5f * (float)(HH - 1));
        const float x0f = floorf(ix), y0f = floorf(iy);
        const int x0 = (int)x0f, y0 = (int)y0f, x1 = x0 + 1, y1 = y0 + 1;
        const float wx1 = ix - x0f, wy1 = iy - y0f;
        const float wx0 = 1.0f - wx1, wy0 = 1.0f - wy1;
        const float v00 = (x0 >= 0 && x0 < WW && y0 >= 0 && y0 < HH) ? 1.0f : 0.0f;
        const float v01 = (x1 >= 0 && x1 < WW && y0 >= 0 && y0 < HH) ? 1.0f : 0.0f;
        const float v10 = (x0 >= 0 && x0 < WW && y1 >= 0 && y1 < HH) ? 1.0f : 0.0f;
        const float v11 = (x1 >= 0 && x1 < WW && y1 >= 0 && y1 < HH) ? 1.0f : 0.0f;
        const float w00 = wy0 * wx0 * v00, w01 = wy0 * wx1 * v01;
        const float w10 = wy1 * wx0 * v10, w11 = wy1 * wx1 * v11;
        const int x0c = min(max(x0, 0), WW - 1), x1c = min(max(x1, 0), WW - 1);
        const int y0c = min(max(y0, 0), HH - 1), y1c = min(max(y1, 0), HH - 1);
        const int o00 = y0c * WW + x0c, o01 = y0c * WW + x1c;
        const int o10 = y1c * WW + x0c, o11 = y1c * WW + x1c;
        const float* p = x + ((size_t)(b * NN + j) * CC + cg * CG) * HW;
        float t00[CG], t01[CG], t10[CG], t11[CG];
#pragma unroll
        for (int c = 0; c < CG; ++c) {
            const float* pc = p + (size_t)c * HW;
            t00[c] = pc[o00]; t01[c] = pc[o01]; t10[c] = pc[o10]; t11[c] = pc[o11];
        }
#pragma unroll
        for (int c = 0; c < CG; ++c) {
            const float s = __builtin_fmaf(w00, t00[c], __builtin_fmaf(w01, t01[c],
                            __builtin_fmaf(w10, t10[c], w11 * t11[c])));
            acc[c] = fmaxf(acc[c], s);
        }
    }
    float* op = out + ((size_t)bi * CC + cg * CG) * HW + h * WW + w;
#pragma unroll
    for (int c = 0; c < CG; ++c) op[(size_t)c * HW] = acc[c];
}

extern "C" void kernel_launch(void* const* d_in, const int* in_sizes, int n_in,
                              void* d_out, int out_size, void* d_ws, size_t ws_size,
                              hipStream_t stream) {
    const float* x = (const float*)d_in[0];
    const float* T = (const float*)d_in[3];
    float* out = (float*)d_out;

    const size_t xt_bytes = (size_t)BB * NN * HH * WW * CC * sizeof(float); // 129 MB
    if (ws_size >= xt_bytes) {
        float* xt = (float*)d_ws;
        const int grid1 = BB * NN * HH * NTW;   // 8000
        transpose_chw_hwc<<<grid1, 256, 0, stream>>>(x, xt);
        const int grid2 = BB * NN * HH * NTW;   // 8000
        fuse_gather<<<grid2, 512, 0, stream>>>(xt, T, out);
    } else {
        const int total = BB * NN * HW * NCG;
        where2comm_fuse_fallback<<<(total + 255) / 256, 256, 0, stream>>>(x, T, out);
    }
}

// Round 9
// 132.922 us; speedup vs baseline: 2.5347x; 1.2613x over previous
//
#include <hip/hip_runtime.h>
#include <math.h>

// Problem constants: B=4, N=L=5, C=64, H=100, W=252
#define BB 4
#define NN 5
#define CC 64
#define HH 100
#define WW 252
#define HW (HH * WW)
#define TILE_W 64
#define NTW ((WW + TILE_W - 1) / TILE_W)   // 4 tiles per row
#define CSTR 9                              // coord LDS stride (conflict-free)
#define NXCD 8

typedef _Float16 h2v __attribute__((ext_vector_type(2)));
typedef _Float16 h4v __attribute__((ext_vector_type(4)));

// ---------- pass 1: transpose+quantize x (f32, BN,C,H,W) -> xt (f16, BN,H,W,C) ----------
__global__ __launch_bounds__(256) void transpose_chw_hwc(
    const float* __restrict__ x, _Float16* __restrict__ xt)
{
    __shared__ float tile[CC][TILE_W + 1];
    const int blk = blockIdx.x;
    const int wt  = blk % NTW;
    const int h   = (blk / NTW) % HH;
    const int bn  = blk / (NTW * HH);
    const int w0  = wt * TILE_W;

    const int lane = threadIdx.x & 63;
    const int sub  = threadIdx.x >> 6;    // 0..3

#pragma unroll
    for (int it = 0; it < 16; ++it) {     // read coalesced along w
        const int c = sub + 4 * it;
        const int w = w0 + lane;
        if (w < WW)
            tile[c][lane] = x[((size_t)(bn * CC + c) * HH + h) * WW + w];
    }
    __syncthreads();
    // write as half2 units: unit = (px, c-pair); coalesced along c.
#pragma unroll
    for (int it = 0; it < 8; ++it) {
        const int unit = it * 256 + threadIdx.x;   // 0..2047
        const int px = unit >> 5;                  // 0..63
        const int c2 = unit & 31;                  // 0..31
        const int w  = w0 + px;
        if (w < WW) {
            h2v hv;
            hv[0] = (_Float16)tile[2 * c2 + 0][px];
            hv[1] = (_Float16)tile[2 * c2 + 1][px];
            *(h2v*)(xt + ((((size_t)bn * HH + h) * WW + w) * CC + 2 * c2)) = hv;
        }
    }
}

// ---------- pass 2: fp16 gather, 512 threads / 8 waves per block ----------
__global__ __launch_bounds__(512) void fuse_gather(
    const _Float16* __restrict__ xt,  // (BN, H, W, C) fp16
    const float* __restrict__ T,      // (B, L, L, 4, 4)
    float* __restrict__ out)          // (BN, C, H, W) fp32
{
    __shared__ float coord[NN][TILE_W][CSTR];   // per (j, pixel): 4 offsets + 4 weights
    __shared__ float tile[TILE_W][CC + 1];      // per (pixel, channel) result

    // XCD chunked swizzle (bijective: 8000 % 8 == 0)
    const int cpx = gridDim.x / NXCD;
    const int blk = (blockIdx.x % NXCD) * cpx + blockIdx.x / NXCD;

    const int wt  = blk % NTW;
    const int h   = (blk / NTW) % HH;
    const int bi  = blk / (NTW * HH);
    const int b   = bi / NN;
    const int i   = bi % NN;
    const int w0  = wt * TILE_W;

    const int lane = threadIdx.x & 63;
    const int wv   = threadIdx.x >> 6;   // 0..7

    // ---- phase 0: waves 0..4 each compute one j's coords; lane = pixel.
    if (wv < NN) {
        const int jj = wv;
        const int w  = w0 + lane;
        const float gx = -1.0f + 2.0f * (float)w / (float)(WW - 1);
        const float gy = -1.0f + 2.0f * (float)h / (float)(HH - 1);
        const float sHW = (float)HH / (float)WW;
        const float sWH = (float)WW / (float)HH;
        const float sW  = 2.5f / (float)WW;
        const float sH  = 2.5f / (float)HH;

        const float* Tm = T + ((size_t)(b * NN + i) * NN + jj) * 16;
        const float m00 = Tm[0];
        const float m01 = Tm[1] * sHW;
        const float m02 = Tm[3] * sW;
        const float m10 = Tm[4] * sWH;
        const float m11 = Tm[5];
        const float m12 = Tm[7] * sH;

        const float cx = __builtin_fmaf(m00, gx, __builtin_fmaf(m01, gy, m02));
        const float cy = __builtin_fmaf(m10, gx, __builtin_fmaf(m11, gy, m12));
        const float ix = (cx + 1.0f) * (0.5f * (float)(WW - 1));
        const float iy = (cy + 1.0f) * (0.5f * (float)(HH - 1));

        const float x0f = floorf(ix);
        const float y0f = floorf(iy);
        const int x0 = (int)x0f, y0 = (int)y0f;
        const int x1 = x0 + 1,  y1 = y0 + 1;

        const float wx1 = ix - x0f, wy1 = iy - y0f;
        const float wx0 = 1.0f - wx1, wy0 = 1.0f - wy1;

        const float v00 = (x0 >= 0 && x0 < WW && y0 >= 0 && y0 < HH) ? 1.0f : 0.0f;
        const float v01 = (x1 >= 0 && x1 < WW && y0 >= 0 && y0 < HH) ? 1.0f : 0.0f;
        const float v10 = (x0 >= 0 && x0 < WW && y1 >= 0 && y1 < HH) ? 1.0f : 0.0f;
        const float v11 = (x1 >= 0 && x1 < WW && y1 >= 0 && y1 < HH) ? 1.0f : 0.0f;

        const int x0c = min(max(x0, 0), WW - 1);
        const int x1c = min(max(x1, 0), WW - 1);
        const int y0c = min(max(y0, 0), HH - 1);
        const int y1c = min(max(y1, 0), HH - 1);

        float* cd = coord[jj][lane];
        cd[0] = __int_as_float(y0c * WW + x0c);
        cd[1] = __int_as_float(y0c * WW + x1c);
        cd[2] = __int_as_float(y1c * WW + x0c);
        cd[3] = __int_as_float(y1c * WW + x1c);
        cd[4] = wy0 * wx0 * v00;
        cd[5] = wy0 * wx1 * v01;
        cd[6] = wy1 * wx0 * v10;
        cd[7] = wy1 * wx1 * v11;
    }
    __syncthreads();

    // ---- phase A: wave wv owns pixels wv*8 .. wv*8+7 (2 iters x 4 groups).
    // lane = (group g = lane>>4 -> pixel, channel-quad = (lane&15)*4).
    // Each tap: 8B load of 4 fp16; blend via mixed-precision fma into fp32.
    {
        const int g   = lane >> 4;
        const int ch4 = (lane & 15) * 4;

#pragma unroll
        for (int it = 0; it < 2; ++it) {
            const int p = wv * 8 + it * 4 + g;
            const bool valid = (w0 + p < WW);
            float a0 = -INFINITY, a1 = -INFINITY, a2 = -INFINITY, a3 = -INFINITY;
#pragma unroll
            for (int j = 0; j < NN; ++j) {
                const float* cd = coord[j][p];
                const int o00 = __float_as_int(cd[0]);
                const int o01 = __float_as_int(cd[1]);
                const int o10 = __float_as_int(cd[2]);
                const int o11 = __float_as_int(cd[3]);
                const float w00 = cd[4], w01 = cd[5], w10 = cd[6], w11 = cd[7];

                const _Float16* pj = xt + (size_t)(b * NN + j) * HW * CC;
                const h4v t00 = *(const h4v*)(pj + (size_t)o00 * CC + ch4);
                const h4v t01 = *(const h4v*)(pj + (size_t)o01 * CC + ch4);
                const h4v t10 = *(const h4v*)(pj + (size_t)o10 * CC + ch4);
                const h4v t11 = *(const h4v*)(pj + (size_t)o11 * CC + ch4);

                float s;
                s = __builtin_fmaf(w00, (float)t00[0], __builtin_fmaf(w01, (float)t01[0],
                    __builtin_fmaf(w10, (float)t10[0], w11 * (float)t11[0])));
                a0 = fmaxf(a0, s);
                s = __builtin_fmaf(w00, (float)t00[1], __builtin_fmaf(w01, (float)t01[1],
                    __builtin_fmaf(w10, (float)t10[1], w11 * (float)t11[1])));
                a1 = fmaxf(a1, s);
                s = __builtin_fmaf(w00, (float)t00[2], __builtin_fmaf(w01, (float)t01[2],
                    __builtin_fmaf(w10, (float)t10[2], w11 * (float)t11[2])));
                a2 = fmaxf(a2, s);
                s = __builtin_fmaf(w00, (float)t00[3], __builtin_fmaf(w01, (float)t01[3],
                    __builtin_fmaf(w10, (float)t10[3], w11 * (float)t11[3])));
                a3 = fmaxf(a3, s);
            }
            if (valid) {
                float* tp = &tile[p][ch4];
                tp[0] = a0; tp[1] = a1; tp[2] = a2; tp[3] = a3;
            }
        }
    }
    __syncthreads();

    // ---- phase B: float4 stores along w. unit = (c, w-quad); 2 units/thread.
#pragma unroll
    for (int rep = 0; rep < 2; ++rep) {
        const int unit = threadIdx.x + 512 * rep;   // 0..1023
        const int q = unit & 15;                    // w-quad
        const int c = unit >> 4;                    // 0..63
        const int w = w0 + 4 * q;
        if (w < WW) {
            float4 v;
            v.x = tile[4 * q + 0][c];
            v.y = tile[4 * q + 1][c];
            v.z = tile[4 * q + 2][c];
            v.w = tile[4 * q + 3][c];
            *(float4*)(out + ((size_t)bi * CC + c) * HW + h * WW + w) = v;
        }
    }
}

// ---------- fallback (round-4 kernel) if workspace is too small ----------
#define CG 16
#define NCG (CC / CG)
__global__ __launch_bounds__(256, 4) void where2comm_fuse_fallback(
    const float* __restrict__ x, const float* __restrict__ T,
    float* __restrict__ out)
{
    const int tid = blockIdx.x * blockDim.x + threadIdx.x;
    const int total = BB * NN * HW * NCG;
    if (tid >= total) return;
    const int w = tid % WW;
    int t2 = tid / WW;
    const int h = t2 % HH;
    t2 /= HH;
    const int bi = t2 % (BB * NN);
    const int cg = t2 / (BB * NN);
    const int b = bi / NN, i = bi % NN;
    const float gx = -1.0f + 2.0f * (float)w / (float)(WW - 1);
    const float gy = -1.0f + 2.0f * (float)h / (float)(HH - 1);
    float acc[CG];
#pragma unroll
    for (int c = 0; c < CG; ++c) acc[c] = -INFINITY;
    const float sHW = (float)HH / (float)WW, sWH = (float)WW / (float)HH;
    const float sW = 2.5f / (float)WW, sH = 2.5f / (float)HH;
    for (int j = 0; j < NN; ++j) {
        const float* Tm = T + ((size_t)(b * NN + i) * NN + j) * 16;
        const float m00 = Tm[0], m01 = Tm[1] * sHW, m02 = Tm[3] * sW;
        const float m10 = Tm[4] * sWH, m11 = Tm[5], m12 = Tm[7] * sH;
        const float cx = __builtin_fmaf(m00, gx, __builtin_fmaf(m01, gy, m02));
        const float cy = __builtin_fmaf(m10, gx, __builtin_fmaf(m11, gy, m12));
        const float ix = (cx + 1.0f) * (0.5f * (float)(WW - 1));
        const float iy = (cy + 1.0f) * (0.5f * (float)(HH - 1));
        const float x0f = floorf(ix), y0f = floorf(iy);
        const int x0 = (int)x0f, y0 = (int)y0f, x1 = x0 + 1, y1 = y0 + 1;
        const float wx1 = ix - x0f, wy1 = iy - y0f;
        const float wx0 = 1.0f - wx1, wy0 = 1.0f - wy1;
        const float v00 = (x0 >= 0 && x0 < WW && y0 >= 0 && y0 < HH) ? 1.0f : 0.0f;
        const float v01 = (x1 >= 0 && x1 < WW && y0 >= 0 && y0 < HH) ? 1.0f : 0.0f;
        const float v10 = (x0 >= 0 && x0 < WW && y1 >= 0 && y1 < HH) ? 1.0f : 0.0f;
        const float v11 = (x1 >= 0 && x1 < WW && y1 >= 0 && y1 < HH) ? 1.0f : 0.0f;
        const float w00 = wy0 * wx0 * v00, w01 = wy0 * wx1 * v01;
        const float w10 = wy1 * wx0 * v10, w11 = wy1 * wx1 * v11;
        const int x0c = min(max(x0, 0), WW - 1), x1c = min(max(x1, 0), WW - 1);
        const int y0c = min(max(y0, 0), HH - 1), y1c = min(max(y1, 0), HH - 1);
        const int o00 = y0c * WW + x0c, o01 = y0c * WW + x1c;
        const int o10 = y1c * WW + x0c, o11 = y1c * WW + x1c;
        const float* p = x + ((size_t)(b * NN + j) * CC + cg * CG) * HW;
        float t00[CG], t01[CG], t10[CG], t11[CG];
#pragma unroll
        for (int c = 0; c < CG; ++c) {
            const float* pc = p + (size_t)c * HW;
            t00[c] = pc[o00]; t01[c] = pc[o01]; t10[c] = pc[o10]; t11[c] = pc[o11];
        }
#pragma unroll
        for (int c = 0; c < CG; ++c) {
            const float s = __builtin_fmaf(w00, t00[c], __builtin_fmaf(w01, t01[c],
                            __builtin_fmaf(w10, t10[c], w11 * t11[c])));
            acc[c] = fmaxf(acc[c], s);
        }
    }
    float* op = out + ((size_t)bi * CC + cg * CG) * HW + h * WW + w;
#pragma unroll
    for (int c = 0; c < CG; ++c) op[(size_t)c * HW] = acc[c];
}

extern "C" void kernel_launch(void* const* d_in, const int* in_sizes, int n_in,
                              void* d_out, int out_size, void* d_ws, size_t ws_size,
                              hipStream_t stream) {
    const float* x = (const float*)d_in[0];
    const float* T = (const float*)d_in[3];
    float* out = (float*)d_out;

    const size_t xt_bytes = (size_t)BB * NN * HH * WW * CC * sizeof(_Float16); // 64.5 MB
    if (ws_size >= xt_bytes) {
        _Float16* xt = (_Float16*)d_ws;
        const int grid1 = BB * NN * HH * NTW;   // 8000
        transpose_chw_hwc<<<grid1, 256, 0, stream>>>(x, xt);
        const int grid2 = BB * NN * HH * NTW;   // 8000
        fuse_gather<<<grid2, 512, 0, stream>>>(xt, T, out);
    } else {
        const int total = BB * NN * HW * NCG;
        where2comm_fuse_fallback<<<(total + 255) / 256, 256, 0, stream>>>(x, T, out);
    }
}

// Round 10
// 109.325 us; speedup vs baseline: 3.0818x; 1.2158x over previous
//
#include <hip/hip_runtime.h>
#include <math.h>

// Problem constants: B=4, N=L=5, C=64, H=100, W=252
#define BB 4
#define NN 5
#define CC 64
#define HH 100
#define WW 252
#define HW (HH * WW)
#define TILE_W 64
#define NTW ((WW + TILE_W - 1) / TILE_W)   // 4 tiles per row
#define NXCD 8
#define PAD_B (64 * 1024)                   // guard pad before xt (o_base >= -(W+1) px = -32.4KB)
#define PAD_A (128 * 1024)                  // guard pad after xt (o up to (H+1)*W+W+1 px = +64.7KB)

typedef _Float16 h2v __attribute__((ext_vector_type(2)));
typedef _Float16 h8v __attribute__((ext_vector_type(8)));

// ---------- pass 1: transpose+quantize x (f32, BN,C,H,W) -> xt (f16, BN,H,W,C) ----------
__global__ __launch_bounds__(256) void transpose_chw_hwc(
    const float* __restrict__ x, _Float16* __restrict__ xt)
{
    __shared__ float tile[CC][TILE_W + 1];
    const int blk = blockIdx.x;
    const int wt  = blk % NTW;
    const int h   = (blk / NTW) % HH;
    const int bn  = blk / (NTW * HH);
    const int w0  = wt * TILE_W;

    const int lane = threadIdx.x & 63;
    const int sub  = threadIdx.x >> 6;    // 0..3

#pragma unroll
    for (int it = 0; it < 16; ++it) {     // read coalesced along w
        const int c = sub + 4 * it;
        const int w = w0 + lane;
        if (w < WW)
            tile[c][lane] = x[((size_t)(bn * CC + c) * HH + h) * WW + w];
    }
    __syncthreads();
    // write as half2 units: unit = (px, c-pair); coalesced along c.
#pragma unroll
    for (int it = 0; it < 8; ++it) {
        const int unit = it * 256 + threadIdx.x;   // 0..2047
        const int px = unit >> 5;                  // 0..63
        const int c2 = unit & 31;                  // 0..31
        const int w  = w0 + px;
        if (w < WW) {
            h2v hv;
            hv[0] = (_Float16)tile[2 * c2 + 0][px];
            hv[1] = (_Float16)tile[2 * c2 + 1][px];
            *(h2v*)(xt + ((((size_t)bn * HH + h) * WW + w) * CC + 2 * c2)) = hv;
        }
    }
}

// ---------- pass 2: fp16 gather, one base address per (j,pixel) ----------
// Taps live at pixel offsets {o, o+1, o+W, o+W+1}: derive 3 of 4 addresses by
// constant adds (tap+1 folds into the 128B load imm-offset). Validity is folded
// into weights from UNCLAMPED coords; o_base is range-clamped only so derived
// addresses stay inside [xt - PAD_B, xt_end + PAD_A) (weight==0 taps may read
// garbage pad bytes = finite fp16, never NaN/Inf).
__global__ __launch_bounds__(512) void fuse_gather(
    const _Float16* __restrict__ xt,  // (BN, H, W, C) fp16 (padded alloc)
    const float* __restrict__ T,      // (B, L, L, 4, 4)
    float* __restrict__ out)          // (BN, C, H, W) fp32
{
    __shared__ float coord[NN][TILE_W][5];      // per (j, pixel): oc + 4 weights
    __shared__ float tile[TILE_W][CC + 1];      // per (pixel, channel) result

    // XCD chunked swizzle (bijective: 8000 % 8 == 0)
    const int cpx = gridDim.x / NXCD;
    const int blk = (blockIdx.x % NXCD) * cpx + blockIdx.x / NXCD;

    const int wt  = blk % NTW;
    const int h   = (blk / NTW) % HH;
    const int bi  = blk / (NTW * HH);
    const int b   = bi / NN;
    const int i   = bi % NN;
    const int w0  = wt * TILE_W;

    const int lane = threadIdx.x & 63;
    const int wv   = threadIdx.x >> 6;   // 0..7

    // ---- phase 0: waves 0..4 each compute one j's coords; lane = pixel.
    if (wv < NN) {
        const int jj = wv;
        const int w  = w0 + lane;
        const float gx = -1.0f + 2.0f * (float)w / (float)(WW - 1);
        const float gy = -1.0f + 2.0f * (float)h / (float)(HH - 1);
        const float sHW = (float)HH / (float)WW;
        const float sWH = (float)WW / (float)HH;
        const float sW  = 2.5f / (float)WW;
        const float sH  = 2.5f / (float)HH;

        const float* Tm = T + ((size_t)(b * NN + i) * NN + jj) * 16;
        const float m00 = Tm[0];
        const float m01 = Tm[1] * sHW;
        const float m02 = Tm[3] * sW;
        const float m10 = Tm[4] * sWH;
        const float m11 = Tm[5];
        const float m12 = Tm[7] * sH;

        const float cx = __builtin_fmaf(m00, gx, __builtin_fmaf(m01, gy, m02));
        const float cy = __builtin_fmaf(m10, gx, __builtin_fmaf(m11, gy, m12));
        const float ix = (cx + 1.0f) * (0.5f * (float)(WW - 1));
        const float iy = (cy + 1.0f) * (0.5f * (float)(HH - 1));

        const float x0f = floorf(ix);
        const float y0f = floorf(iy);
        const int x0 = (int)x0f, y0 = (int)y0f;
        const int x1 = x0 + 1,  y1 = y0 + 1;

        const float wx1 = ix - x0f, wy1 = iy - y0f;
        const float wx0 = 1.0f - wx1, wy0 = 1.0f - wy1;

        // validity from TRUE coords
        const float v00 = (x0 >= 0 && x0 < WW && y0 >= 0 && y0 < HH) ? 1.0f : 0.0f;
        const float v01 = (x1 >= 0 && x1 < WW && y0 >= 0 && y0 < HH) ? 1.0f : 0.0f;
        const float v10 = (x0 >= 0 && x0 < WW && y1 >= 0 && y1 < HH) ? 1.0f : 0.0f;
        const float v11 = (x1 >= 0 && x1 < WW && y1 >= 0 && y1 < HH) ? 1.0f : 0.0f;

        // address-safety clamp only (engages only when the affected taps have weight 0)
        const int x0s = min(max(x0, -1), WW);
        const int y0s = min(max(y0, -1), HH);
        const int oc  = (y0s * WW + x0s) * CC;   // element offset of tap00's channel row

        float* cd = coord[jj][lane];
        cd[0] = __int_as_float(oc);
        cd[1] = wy0 * wx0 * v00;
        cd[2] = wy0 * wx1 * v01;
        cd[3] = wy1 * wx0 * v10;
        cd[4] = wy1 * wx1 * v11;
    }
    __syncthreads();

    // ---- phase A: wave wv owns pixels wv*8..wv*8+7; 8 lanes per pixel,
    // 8 channels per lane (one dwordx4 fp16 load per tap).
    {
        const int g   = lane >> 3;         // pixel within wave's 8
        const int ch8 = (lane & 7) * 8;    // channel start
        const int p   = wv * 8 + g;

        if (w0 + p < WW) {
            float a0 = -INFINITY, a1 = -INFINITY, a2 = -INFINITY, a3 = -INFINITY;
            float a4 = -INFINITY, a5 = -INFINITY, a6 = -INFINITY, a7 = -INFINITY;

#pragma unroll
            for (int j = 0; j < NN; ++j) {
                const float* cd = coord[j][p];
                const int   oc  = __float_as_int(cd[0]);
                const float w00 = cd[1], w01 = cd[2], w10 = cd[3], w11 = cd[4];

                const _Float16* base0 = xt + (size_t)(b * NN + j) * HW * CC
                                           + (long)oc + ch8;
                const _Float16* base1 = base0 + (long)WW * CC;

                const h8v t00 = *(const h8v*)(base0);
                const h8v t01 = *(const h8v*)(base0 + CC);     // +128 B imm
                const h8v t10 = *(const h8v*)(base1);
                const h8v t11 = *(const h8v*)(base1 + CC);     // +128 B imm

                float s;
                s = __builtin_fmaf(w00, (float)t00[0], __builtin_fmaf(w01, (float)t01[0],
                    __builtin_fmaf(w10, (float)t10[0], w11 * (float)t11[0])));
                a0 = fmaxf(a0, s);
                s = __builtin_fmaf(w00, (float)t00[1], __builtin_fmaf(w01, (float)t01[1],
                    __builtin_fmaf(w10, (float)t10[1], w11 * (float)t11[1])));
                a1 = fmaxf(a1, s);
                s = __builtin_fmaf(w00, (float)t00[2], __builtin_fmaf(w01, (float)t01[2],
                    __builtin_fmaf(w10, (float)t10[2], w11 * (float)t11[2])));
                a2 = fmaxf(a2, s);
                s = __builtin_fmaf(w00, (float)t00[3], __builtin_fmaf(w01, (float)t01[3],
                    __builtin_fmaf(w10, (float)t10[3], w11 * (float)t11[3])));
                a3 = fmaxf(a3, s);
                s = __builtin_fmaf(w00, (float)t00[4], __builtin_fmaf(w01, (float)t01[4],
                    __builtin_fmaf(w10, (float)t10[4], w11 * (float)t11[4])));
                a4 = fmaxf(a4, s);
                s = __builtin_fmaf(w00, (float)t00[5], __builtin_fmaf(w01, (float)t01[5],
                    __builtin_fmaf(w10, (float)t10[5], w11 * (float)t11[5])));
                a5 = fmaxf(a5, s);
                s = __builtin_fmaf(w00, (float)t00[6], __builtin_fmaf(w01, (float)t01[6],
                    __builtin_fmaf(w10, (float)t10[6], w11 * (float)t11[6])));
                a6 = fmaxf(a6, s);
                s = __builtin_fmaf(w00, (float)t00[7], __builtin_fmaf(w01, (float)t01[7],
                    __builtin_fmaf(w10, (float)t10[7], w11 * (float)t11[7])));
                a7 = fmaxf(a7, s);
            }
            // scalar LDS stores (stride 65 keeps phase-B reads 2-way/bank-free;
            // 8 x b32 once per thread is cheap)
            float* tp = &tile[p][ch8];
            tp[0] = a0; tp[1] = a1; tp[2] = a2; tp[3] = a3;
            tp[4] = a4; tp[5] = a5; tp[6] = a6; tp[7] = a7;
        }
    }
    __syncthreads();

    // ---- phase B: float4 stores along w. unit = (c, w-quad); 2 units/thread.
#pragma unroll
    for (int rep = 0; rep < 2; ++rep) {
        const int unit = threadIdx.x + 512 * rep;   // 0..1023
        const int q = unit & 15;                    // w-quad
        const int c = unit >> 4;                    // 0..63
        const int w = w0 + 4 * q;
        if (w < WW) {
            float4 v;
            v.x = tile[4 * q + 0][c];
            v.y = tile[4 * q + 1][c];
            v.z = tile[4 * q + 2][c];
            v.w = tile[4 * q + 3][c];
            *(float4*)(out + ((size_t)bi * CC + c) * HW + h * WW + w) = v;
        }
    }
}

// ---------- fallback (round-4 kernel) if workspace is too small ----------
#define CG 16
#define NCG (CC / CG)
__global__ __launch_bounds__(256, 4) void where2comm_fuse_fallback(
    const float* __restrict__ x, const float* __restrict__ T,
    float* __restrict__ out)
{
    const int tid = blockIdx.x * blockDim.x + threadIdx.x;
    const int total = BB * NN * HW * NCG;
    if (tid >= total) return;
    const int w = tid % WW;
    int t2 = tid / WW;
    const int h = t2 % HH;
    t2 /= HH;
    const int bi = t2 % (BB * NN);
    const int cg = t2 / (BB * NN);
    const int b = bi / NN, i = bi % NN;
    const float gx = -1.0f + 2.0f * (float)w / (float)(WW - 1);
    const float gy = -1.0f + 2.0f * (float)h / (float)(HH - 1);
    float acc[CG];
#pragma unroll
    for (int c = 0; c < CG; ++c) acc[c] = -INFINITY;
    const float sHW = (float)HH / (float)WW, sWH = (float)WW / (float)HH;
    const float sW = 2.5f / (float)WW, sH = 2.5f / (float)HH;
    for (int j = 0; j < NN; ++j) {
        const float* Tm = T + ((size_t)(b * NN + i) * NN + j) * 16;
        const float m00 = Tm[0], m01 = Tm[1] * sHW, m02 = Tm[3] * sW;
        const float m10 = Tm[4] * sWH, m11 = Tm[5], m12 = Tm[7] * sH;
        const float cx = __builtin_fmaf(m00, gx, __builtin_fmaf(m01, gy, m02));
        const float cy = __builtin_fmaf(m10, gx, __builtin_fmaf(m11, gy, m12));
        const float ix = (cx + 1.0f) * (0.5f * (float)(WW - 1));
        const float iy = (cy + 1.0f) * (0.5f * (float)(HH - 1));
        const float x0f = floorf(ix), y0f = floorf(iy);
        const int x0 = (int)x0f, y0 = (int)y0f, x1 = x0 + 1, y1 = y0 + 1;
        const float wx1 = ix - x0f, wy1 = iy - y0f;
        const float wx0 = 1.0f - wx1, wy0 = 1.0f - wy1;
        const float v00 = (x0 >= 0 && x0 < WW && y0 >= 0 && y0 < HH) ? 1.0f : 0.0f;
        const float v01 = (x1 >= 0 && x1 < WW && y0 >= 0 && y0 < HH) ? 1.0f : 0.0f;
        const float v10 = (x0 >= 0 && x0 < WW && y1 >= 0 && y1 < HH) ? 1.0f : 0.0f;
        const float v11 = (x1 >= 0 && x1 < WW && y1 >= 0 && y1 < HH) ? 1.0f : 0.0f;
        const float w00 = wy0 * wx0 * v00, w01 = wy0 * wx1 * v01;
        const float w10 = wy1 * wx0 * v10, w11 = wy1 * wx1 * v11;
        const int x0c = min(max(x0, 0), WW - 1), x1c = min(max(x1, 0), WW - 1);
        const int y0c = min(max(y0, 0), HH - 1), y1c = min(max(y1, 0), HH - 1);
        const int o00 = y0c * WW + x0c, o01 = y0c * WW + x1c;
        const int o10 = y1c * WW + x0c, o11 = y1c * WW + x1c;
        const float* p = x + ((size_t)(b * NN + j) * CC + cg * CG) * HW;
        float t00[CG], t01[CG], t10[CG], t11[CG];
#pragma unroll
        for (int c = 0; c < CG; ++c) {
            const float* pc = p + (size_t)c * HW;
            t00[c] = pc[o00]; t01[c] = pc[o01]; t10[c] = pc[o10]; t11[c] = pc[o11];
        }
#pragma unroll
        for (int c = 0; c < CG; ++c) {
            const float s = __builtin_fmaf(w00, t00[c], __builtin_fmaf(w01, t01[c],
                            __builtin_fmaf(w10, t10[c], w11 * t11[c])));
            acc[c] = fmaxf(acc[c], s);
        }
    }
    float* op = out + ((size_t)bi * CC + cg * CG) * HW + h * WW + w;
#pragma unroll
    for (int c = 0; c < CG; ++c) op[(size_t)c * HW] = acc[c];
}

extern "C" void kernel_launch(void* const* d_in, const int* in_sizes, int n_in,
                              void* d_out, int out_size, void* d_ws, size_t ws_size,
                              hipStream_t stream) {
    const float* x = (const float*)d_in[0];
    const float* T = (const float*)d_in[3];
    float* out = (float*)d_out;

    const size_t xt_bytes = (size_t)BB * NN * HH * WW * CC * sizeof(_Float16); // 64.5 MB
    if (ws_size >= PAD_B + xt_bytes + PAD_A) {
        _Float16* xt = (_Float16*)((char*)d_ws + PAD_B);
        const int grid1 = BB * NN * HH * NTW;   // 8000
        transpose_chw_hwc<<<grid1, 256, 0, stream>>>(x, xt);
        const int grid2 = BB * NN * HH * NTW;   // 8000
        fuse_gather<<<grid2, 512, 0, stream>>>(xt, T, out);
    } else {
        const int total = BB * NN * HW * NCG;
        where2comm_fuse_fallback<<<(total + 255) / 256, 256, 0, stream>>>(x, T, out);
    }
}

// Round 11
// 101.216 us; speedup vs baseline: 3.3287x; 1.0801x over previous
//
#include <hip/hip_runtime.h>
#include <math.h>

// Problem constants: B=4, N=L=5, C=64, H=100, W=252
#define BB 4
#define NN 5
#define CC 64
#define HH 100
#define WW 252
#define HW (HH * WW)
#define TILE_W 64
#define NTW ((WW + TILE_W - 1) / TILE_W)   // 4 tiles per row
#define NXCD 8
#define PAD_B (64 * 1024)                   // guard pad before xt
#define PAD_A (128 * 1024)                  // guard pad after xt

typedef _Float16 h2v __attribute__((ext_vector_type(2)));
typedef _Float16 h8v __attribute__((ext_vector_type(8)));

// ---------- pass 1: transpose+quantize x (f32, BN,C,H,W) -> xt (f16, BN,H,W,C) ----------
__global__ __launch_bounds__(256) void transpose_chw_hwc(
    const float* __restrict__ x, _Float16* __restrict__ xt)
{
    __shared__ float tile[CC][TILE_W + 1];
    const int blk = blockIdx.x;
    const int wt  = blk % NTW;
    const int h   = (blk / NTW) % HH;
    const int bn  = blk / (NTW * HH);
    const int w0  = wt * TILE_W;

    const int lane = threadIdx.x & 63;
    const int sub  = threadIdx.x >> 6;    // 0..3

#pragma unroll
    for (int it = 0; it < 16; ++it) {     // read coalesced along w
        const int c = sub + 4 * it;
        const int w = w0 + lane;
        if (w < WW)
            tile[c][lane] = x[((size_t)(bn * CC + c) * HH + h) * WW + w];
    }
    __syncthreads();
    // write as half2 units: unit = (px, c-pair); coalesced along c.
#pragma unroll
    for (int it = 0; it < 8; ++it) {
        const int unit = it * 256 + threadIdx.x;   // 0..2047
        const int px = unit >> 5;                  // 0..63
        const int c2 = unit & 31;                  // 0..31
        const int w  = w0 + px;
        if (w < WW) {
            h2v hv;
            hv[0] = (_Float16)tile[2 * c2 + 0][px];
            hv[1] = (_Float16)tile[2 * c2 + 1][px];
            *(h2v*)(xt + ((((size_t)bn * HH + h) * WW + w) * CC + 2 * c2)) = hv;
        }
    }
}

// ---------- pass 2: fp16 gather, packed-half2 blend ----------
// Block order (after XCD chunking): i fastest, then wt, then h, then b.
// The 5 output agents of one (b,h,wt) stripe run back-to-back on one XCD and
// share the same source bands -> L2-resident reuse instead of 2.4x refetch.
__global__ __launch_bounds__(512) void fuse_gather(
    const _Float16* __restrict__ xt,  // (BN, H, W, C) fp16 (padded alloc)
    const float* __restrict__ T,      // (B, L, L, 4, 4)
    float* __restrict__ out)          // (BN, C, H, W) fp32
{
    __shared__ float coord[NN][TILE_W][5];      // per (j, pixel): oc + 4 packed-h2 weights
    __shared__ float tile[TILE_W][CC + 1];      // per (pixel, channel) result

    // XCD chunked swizzle (bijective: 8000 % 8 == 0)
    const int cpx = gridDim.x / NXCD;
    const int blk = (blockIdx.x % NXCD) * cpx + blockIdx.x / NXCD;

    // decompose: b (2000 blocks each) -> hwt (i fastest inside)
    const int b   = blk / (NN * HH * NTW);
    const int r   = blk % (NN * HH * NTW);
    const int i   = r % NN;
    const int hwt = r / NN;           // 0..399
    const int wt  = hwt % NTW;
    const int h   = hwt / NTW;
    const int bi  = b * NN + i;
    const int w0  = wt * TILE_W;

    const int lane = threadIdx.x & 63;
    const int wv   = threadIdx.x >> 6;   // 0..7

    // ---- phase 0: waves 0..4 each compute one j's coords; lane = pixel.
    if (wv < NN) {
        const int jj = wv;
        const int w  = w0 + lane;
        const float gx = -1.0f + 2.0f * (float)w / (float)(WW - 1);
        const float gy = -1.0f + 2.0f * (float)h / (float)(HH - 1);
        const float sHW = (float)HH / (float)WW;
        const float sWH = (float)WW / (float)HH;
        const float sW  = 2.5f / (float)WW;
        const float sH  = 2.5f / (float)HH;

        const float* Tm = T + ((size_t)(b * NN + i) * NN + jj) * 16;
        const float m00 = Tm[0];
        const float m01 = Tm[1] * sHW;
        const float m02 = Tm[3] * sW;
        const float m10 = Tm[4] * sWH;
        const float m11 = Tm[5];
        const float m12 = Tm[7] * sH;

        const float cx = __builtin_fmaf(m00, gx, __builtin_fmaf(m01, gy, m02));
        const float cy = __builtin_fmaf(m10, gx, __builtin_fmaf(m11, gy, m12));
        const float ix = (cx + 1.0f) * (0.5f * (float)(WW - 1));
        const float iy = (cy + 1.0f) * (0.5f * (float)(HH - 1));

        const float x0f = floorf(ix);
        const float y0f = floorf(iy);
        const int x0 = (int)x0f, y0 = (int)y0f;
        const int x1 = x0 + 1,  y1 = y0 + 1;

        const float wx1 = ix - x0f, wy1 = iy - y0f;
        const float wx0 = 1.0f - wx1, wy0 = 1.0f - wy1;

        const float v00 = (x0 >= 0 && x0 < WW && y0 >= 0 && y0 < HH) ? 1.0f : 0.0f;
        const float v01 = (x1 >= 0 && x1 < WW && y0 >= 0 && y0 < HH) ? 1.0f : 0.0f;
        const float v10 = (x0 >= 0 && x0 < WW && y1 >= 0 && y1 < HH) ? 1.0f : 0.0f;
        const float v11 = (x1 >= 0 && x1 < WW && y1 >= 0 && y1 < HH) ? 1.0f : 0.0f;

        // address-safety clamp only (affected taps always carry weight 0)
        const int x0s = min(max(x0, -1), WW);
        const int y0s = min(max(y0, -1), HH);
        const int oc  = (y0s * WW + x0s) * CC;

        // pack each weight as a half2 splat (consumers bit_cast, zero VALU there)
        const _Float16 h00 = (_Float16)(wy0 * wx0 * v00);
        const _Float16 h01 = (_Float16)(wy0 * wx1 * v01);
        const _Float16 h10 = (_Float16)(wy1 * wx0 * v10);
        const _Float16 h11 = (_Float16)(wy1 * wx1 * v11);

        float* cd = coord[jj][lane];
        cd[0] = __int_as_float(oc);
        h2v p00 = {h00, h00}; cd[1] = __builtin_bit_cast(float, p00);
        h2v p01 = {h01, h01}; cd[2] = __builtin_bit_cast(float, p01);
        h2v p10 = {h10, h10}; cd[3] = __builtin_bit_cast(float, p10);
        h2v p11 = {h11, h11}; cd[4] = __builtin_bit_cast(float, p11);
    }
    __syncthreads();

    // ---- phase A: wave wv owns pixels wv*8..wv*8+7; 8 lanes per pixel,
    // 8 channels per lane; blend fully in packed fp16 (pk_fma / pk_max).
    {
        const int g   = lane >> 3;         // pixel within wave's 8
        const int ch8 = (lane & 7) * 8;    // channel start
        const int p   = wv * 8 + g;

        if (w0 + p < WW) {
            const _Float16 NEGINF = (_Float16)(-INFINITY);
            h2v a0 = {NEGINF, NEGINF}, a1 = a0, a2 = a0, a3 = a0;

#pragma unroll
            for (int j = 0; j < NN; ++j) {
                const float* cd = coord[j][p];
                const int oc  = __float_as_int(cd[0]);
                const h2v w00 = __builtin_bit_cast(h2v, cd[1]);
                const h2v w01 = __builtin_bit_cast(h2v, cd[2]);
                const h2v w10 = __builtin_bit_cast(h2v, cd[3]);
                const h2v w11 = __builtin_bit_cast(h2v, cd[4]);

                const _Float16* base0 = xt + (size_t)(b * NN + j) * HW * CC
                                           + (long)oc + ch8;
                const _Float16* base1 = base0 + (long)WW * CC;

                const h8v t00 = *(const h8v*)(base0);
                const h8v t01 = *(const h8v*)(base0 + CC);
                const h8v t10 = *(const h8v*)(base1);
                const h8v t11 = *(const h8v*)(base1 + CC);

#define CHUNK(k, acc)                                                          \
                {                                                              \
                    h2v c00 = __builtin_shufflevector(t00, t00, 2*k, 2*k+1);   \
                    h2v c01 = __builtin_shufflevector(t01, t01, 2*k, 2*k+1);   \
                    h2v c10 = __builtin_shufflevector(t10, t10, 2*k, 2*k+1);   \
                    h2v c11 = __builtin_shufflevector(t11, t11, 2*k, 2*k+1);   \
                    h2v s = c11 * w11;                                         \
                    s = c10 * w10 + s;                                         \
                    s = c01 * w01 + s;                                         \
                    s = c00 * w00 + s;                                         \
                    acc = __builtin_elementwise_max(acc, s);                   \
                }
                CHUNK(0, a0) CHUNK(1, a1) CHUNK(2, a2) CHUNK(3, a3)
#undef CHUNK
            }
            float* tp = &tile[p][ch8];
            tp[0] = (float)a0[0]; tp[1] = (float)a0[1];
            tp[2] = (float)a1[0]; tp[3] = (float)a1[1];
            tp[4] = (float)a2[0]; tp[5] = (float)a2[1];
            tp[6] = (float)a3[0]; tp[7] = (float)a3[1];
        }
    }
    __syncthreads();

    // ---- phase B: float4 stores along w. unit = (c, w-quad); 2 units/thread.
#pragma unroll
    for (int rep = 0; rep < 2; ++rep) {
        const int unit = threadIdx.x + 512 * rep;   // 0..1023
        const int q = unit & 15;                    // w-quad
        const int c = unit >> 4;                    // 0..63
        const int w = w0 + 4 * q;
        if (w < WW) {
            float4 v;
            v.x = tile[4 * q + 0][c];
            v.y = tile[4 * q + 1][c];
            v.z = tile[4 * q + 2][c];
            v.w = tile[4 * q + 3][c];
            *(float4*)(out + ((size_t)bi * CC + c) * HW + h * WW + w) = v;
        }
    }
}

// ---------- fallback (round-4 kernel) if workspace is too small ----------
#define CG 16
#define NCG (CC / CG)
__global__ __launch_bounds__(256, 4) void where2comm_fuse_fallback(
    const float* __restrict__ x, const float* __restrict__ T,
    float* __restrict__ out)
{
    const int tid = blockIdx.x * blockDim.x + threadIdx.x;
    const int total = BB * NN * HW * NCG;
    if (tid >= total) return;
    const int w = tid % WW;
    int t2 = tid / WW;
    const int h = t2 % HH;
    t2 /= HH;
    const int bi = t2 % (BB * NN);
    const int cg = t2 / (BB * NN);
    const int b = bi / NN, i = bi % NN;
    const float gx = -1.0f + 2.0f * (float)w / (float)(WW - 1);
    const float gy = -1.0f + 2.0f * (float)h / (float)(HH - 1);
    float acc[CG];
#pragma unroll
    for (int c = 0; c < CG; ++c) acc[c] = -INFINITY;
    const float sHW = (float)HH / (float)WW, sWH = (float)WW / (float)HH;
    const float sW = 2.5f / (float)WW, sH = 2.5f / (float)HH;
    for (int j = 0; j < NN; ++j) {
        const float* Tm = T + ((size_t)(b * NN + i) * NN + j) * 16;
        const float m00 = Tm[0], m01 = Tm[1] * sHW, m02 = Tm[3] * sW;
        const float m10 = Tm[4] * sWH, m11 = Tm[5], m12 = Tm[7] * sH;
        const float cx = __builtin_fmaf(m00, gx, __builtin_fmaf(m01, gy, m02));
        const float cy = __builtin_fmaf(m10, gx, __builtin_fmaf(m11, gy, m12));
        const float ix = (cx + 1.0f) * (0.5f * (float)(WW - 1));
        const float iy = (cy + 1.0f) * (0.5f * (float)(HH - 1));
        const float x0f = floorf(ix), y0f = floorf(iy);
        const int x0 = (int)x0f, y0 = (int)y0f, x1 = x0 + 1, y1 = y0 + 1;
        const float wx1 = ix - x0f, wy1 = iy - y0f;
        const float wx0 = 1.0f - wx1, wy0 = 1.0f - wy1;
        const float v00 = (x0 >= 0 && x0 < WW && y0 >= 0 && y0 < HH) ? 1.0f : 0.0f;
        const float v01 = (x1 >= 0 && x1 < WW && y0 >= 0 && y0 < HH) ? 1.0f : 0.0f;
        const float v10 = (x0 >= 0 && x0 < WW && y1 >= 0 && y1 < HH) ? 1.0f : 0.0f;
        const float v11 = (x1 >= 0 && x1 < WW && y1 >= 0 && y1 < HH) ? 1.0f : 0.0f;
        const float w00 = wy0 * wx0 * v00, w01 = wy0 * wx1 * v01;
        const float w10 = wy1 * wx0 * v10, w11 = wy1 * wx1 * v11;
        const int x0c = min(max(x0, 0), WW - 1), x1c = min(max(x1, 0), WW - 1);
        const int y0c = min(max(y0, 0), HH - 1), y1c = min(max(y1, 0), HH - 1);
        const int o00 = y0c * WW + x0c, o01 = y0c * WW + x1c;
        const int o10 = y1c * WW + x0c, o11 = y1c * WW + x1c;
        const float* p = x + ((size_t)(b * NN + j) * CC + cg * CG) * HW;
        float t00[CG], t01[CG], t10[CG], t11[CG];
#pragma unroll
        for (int c = 0; c < CG; ++c) {
            const float* pc = p + (size_t)c * HW;
            t00[c] = pc[o00]; t01[c] = pc[o01]; t10[c] = pc[o10]; t11[c] = pc[o11];
        }
#pragma unroll
        for (int c = 0; c < CG; ++c) {
            const float s = __builtin_fmaf(w00, t00[c], __builtin_fmaf(w01, t01[c],
                            __builtin_fmaf(w10, t10[c], w11 * t11[c])));
            acc[c] = fmaxf(acc[c], s);
        }
    }
    float* op = out + ((size_t)bi * CC + cg * CG) * HW + h * WW + w;
#pragma unroll
    for (int c = 0; c < CG; ++c) op[(size_t)c * HW] = acc[c];
}

extern "C" void kernel_launch(void* const* d_in, const int* in_sizes, int n_in,
                              void* d_out, int out_size, void* d_ws, size_t ws_size,
                              hipStream_t stream) {
    const float* x = (const float*)d_in[0];
    const float* T = (const float*)d_in[3];
    float* out = (float*)d_out;

    const size_t xt_bytes = (size_t)BB * NN * HH * WW * CC * sizeof(_Float16); // 64.5 MB
    if (ws_size >= PAD_B + xt_bytes + PAD_A) {
        _Float16* xt = (_Float16*)((char*)d_ws + PAD_B);
        const int grid1 = BB * NN * HH * NTW;   // 8000
        transpose_chw_hwc<<<grid1, 256, 0, stream>>>(x, xt);
        const int grid2 = BB * NN * HH * NTW;   // 8000
        fuse_gather<<<grid2, 512, 0, stream>>>(xt, T, out);
    } else {
        const int total = BB * NN * HW * NCG;
        where2comm_fuse_fallback<<<(total + 255) / 256, 256, 0, stream>>>(x, T, out);
    }
}

// Round 15
// 99.600 us; speedup vs baseline: 3.3827x; 1.0162x over previous
//
#include <hip/hip_runtime.h>
#include <math.h>

// Problem constants: B=4, N=L=5, C=64, H=100, W=252
#define BB 4
#define NN 5
#define CC 64
#define HH 100
#define WW 252
#define HW (HH * WW)
#define TILE_W 64
#define NTW ((WW + TILE_W - 1) / TILE_W)   // 4 tiles per row
#define NXCD 8
#define PAD_B (64 * 1024)                   // guard pad before xt
#define PAD_A (128 * 1024)                  // guard pad after xt
#define XT_BYTES ((size_t)BB * NN * HH * WW * CC * 2)   // 64,512,000

typedef _Float16 h2v __attribute__((ext_vector_type(2)));
typedef _Float16 h8v __attribute__((ext_vector_type(8)));
typedef float    f4v __attribute__((ext_vector_type(4)));

// ---------- pass 1: transpose+quantize x (f32, BN,C,H,W) -> xt (f16, BN,H,W,C) ----------
// First 48 blocks additionally zero the guard pads so weight-0 taps always read
// finite values (first-call d_ws is uninitialized; NaN bits would be fragile).
__global__ __launch_bounds__(256) void transpose_chw_hwc(
    const float* __restrict__ x, _Float16* __restrict__ xt, char* __restrict__ wsbase)
{
    if (blockIdx.x < 48) {                 // 48*256*16B = 196608 = PAD_B + PAD_A
        const int u = blockIdx.x * 256 + threadIdx.x;
        f4v z = {0.0f, 0.0f, 0.0f, 0.0f};
        char* dst = (u < PAD_B / 16)
                  ? wsbase + (size_t)u * 16
                  : wsbase + PAD_B + XT_BYTES + (size_t)(u - PAD_B / 16) * 16;
        *(f4v*)dst = z;
    }

    __shared__ float tile[CC][TILE_W + 1];
    const int blk = blockIdx.x;
    const int wt  = blk % NTW;
    const int h   = (blk / NTW) % HH;
    const int bn  = blk / (NTW * HH);
    const int w0  = wt * TILE_W;

    const int lane = threadIdx.x & 63;
    const int sub  = threadIdx.x >> 6;    // 0..3

#pragma unroll
    for (int it = 0; it < 16; ++it) {     // read coalesced along w
        const int c = sub + 4 * it;
        const int w = w0 + lane;
        if (w < WW)
            tile[c][lane] = x[((size_t)(bn * CC + c) * HH + h) * WW + w];
    }
    __syncthreads();
#pragma unroll
    for (int it = 0; it < 8; ++it) {      // write half2 units, coalesced along c
        const int unit = it * 256 + threadIdx.x;   // 0..2047
        const int px = unit >> 5;
        const int c2 = unit & 31;
        const int w  = w0 + px;
        if (w < WW) {
            h2v hv;
            hv[0] = (_Float16)tile[2 * c2 + 0][px];
            hv[1] = (_Float16)tile[2 * c2 + 1][px];
            *(h2v*)(xt + ((((size_t)bn * HH + h) * WW + w) * CC + 2 * c2)) = hv;
        }
    }
}

// ---------- pass 2: fp16 gather, packed-half2 blend (round-11 green structure) ----------
__global__ __launch_bounds__(512) void fuse_gather(
    const _Float16* __restrict__ xt,  // (BN, H, W, C) fp16 (padded alloc)
    const float* __restrict__ T,      // (B, L, L, 4, 4)
    float* __restrict__ out)          // (BN, C, H, W) fp32
{
    __shared__ float coord[NN][TILE_W][5];      // per (j, pixel): oc + 4 packed-h2 weights
    __shared__ float tile[TILE_W][CC + 1];      // per (pixel, channel) result

    // XCD chunked swizzle (bijective: 8000 % 8 == 0)
    const int cpx = gridDim.x / NXCD;
    const int blk = (blockIdx.x % NXCD) * cpx + blockIdx.x / NXCD;

    // decompose: b (2000 blocks each) -> hwt (i fastest inside)
    const int b   = blk / (NN * HH * NTW);
    const int r   = blk % (NN * HH * NTW);
    const int i   = r % NN;
    const int hwt = r / NN;           // 0..399
    const int wt  = hwt % NTW;
    const int h   = hwt / NTW;
    const int bi  = b * NN + i;
    const int w0  = wt * TILE_W;

    const int lane = threadIdx.x & 63;
    const int wv   = threadIdx.x >> 6;   // 0..7

    // ---- phase 0: waves 0..4 each compute one j's coords; lane = pixel.
    if (wv < NN) {
        const int jj = wv;
        const int w  = w0 + lane;
        const float gx = -1.0f + 2.0f * (float)w / (float)(WW - 1);
        const float gy = -1.0f + 2.0f * (float)h / (float)(HH - 1);
        const float sHW = (float)HH / (float)WW;
        const float sWH = (float)WW / (float)HH;
        const float sW  = 2.5f / (float)WW;
        const float sH  = 2.5f / (float)HH;

        const float* Tm = T + ((size_t)(b * NN + i) * NN + jj) * 16;
        const float m00 = Tm[0];
        const float m01 = Tm[1] * sHW;
        const float m02 = Tm[3] * sW;
        const float m10 = Tm[4] * sWH;
        const float m11 = Tm[5];
        const float m12 = Tm[7] * sH;

        const float cx = __builtin_fmaf(m00, gx, __builtin_fmaf(m01, gy, m02));
        const float cy = __builtin_fmaf(m10, gx, __builtin_fmaf(m11, gy, m12));
        const float ix = (cx + 1.0f) * (0.5f * (float)(WW - 1));
        const float iy = (cy + 1.0f) * (0.5f * (float)(HH - 1));

        const float x0f = floorf(ix);
        const float y0f = floorf(iy);
        const int x0 = (int)x0f, y0 = (int)y0f;
        const int x1 = x0 + 1,  y1 = y0 + 1;

        const float wx1 = ix - x0f, wy1 = iy - y0f;
        const float wx0 = 1.0f - wx1, wy0 = 1.0f - wy1;

        const float v00 = (x0 >= 0 && x0 < WW && y0 >= 0 && y0 < HH) ? 1.0f : 0.0f;
        const float v01 = (x1 >= 0 && x1 < WW && y0 >= 0 && y0 < HH) ? 1.0f : 0.0f;
        const float v10 = (x0 >= 0 && x0 < WW && y1 >= 0 && y1 < HH) ? 1.0f : 0.0f;
        const float v11 = (x1 >= 0 && x1 < WW && y1 >= 0 && y1 < HH) ? 1.0f : 0.0f;

        // address-safety clamp only (affected taps always carry weight 0)
        const int x0s = min(max(x0, -1), WW);
        const int y0s = min(max(y0, -1), HH);
        const int oc  = (y0s * WW + x0s) * CC;

        // pack each weight as a half2 splat
        const _Float16 h00 = (_Float16)(wy0 * wx0 * v00);
        const _Float16 h01 = (_Float16)(wy0 * wx1 * v01);
        const _Float16 h10 = (_Float16)(wy1 * wx0 * v10);
        const _Float16 h11 = (_Float16)(wy1 * wx1 * v11);

        float* cd = coord[jj][lane];
        cd[0] = __int_as_float(oc);
        h2v p00 = {h00, h00}; cd[1] = __builtin_bit_cast(float, p00);
        h2v p01 = {h01, h01}; cd[2] = __builtin_bit_cast(float, p01);
        h2v p10 = {h10, h10}; cd[3] = __builtin_bit_cast(float, p10);
        h2v p11 = {h11, h11}; cd[4] = __builtin_bit_cast(float, p11);
    }
    __syncthreads();

    // ---- phase A: wave wv owns pixels wv*8..wv*8+7; 8 lanes per pixel,
    // 8 channels per lane; blend fully in packed fp16 (pk_fma / pk_max).
    {
        const int g   = lane >> 3;         // pixel within wave's 8
        const int ch8 = (lane & 7) * 8;    // channel start
        const int p   = wv * 8 + g;

        if (w0 + p < WW) {
            const _Float16 NEGINF = (_Float16)(-INFINITY);
            h2v a0 = {NEGINF, NEGINF}, a1 = a0, a2 = a0, a3 = a0;

#pragma unroll
            for (int j = 0; j < NN; ++j) {
                const float* cd = coord[j][p];
                const int oc  = __float_as_int(cd[0]);
                const h2v w00 = __builtin_bit_cast(h2v, cd[1]);
                const h2v w01 = __builtin_bit_cast(h2v, cd[2]);
                const h2v w10 = __builtin_bit_cast(h2v, cd[3]);
                const h2v w11 = __builtin_bit_cast(h2v, cd[4]);

                const _Float16* base0 = xt + (size_t)(b * NN + j) * HW * CC
                                           + (long)oc + ch8;
                const _Float16* base1 = base0 + (long)WW * CC;

                const h8v t00 = *(const h8v*)(base0);
                const h8v t01 = *(const h8v*)(base0 + CC);
                const h8v t10 = *(const h8v*)(base1);
                const h8v t11 = *(const h8v*)(base1 + CC);

#define CHUNK(k, acc)                                                          \
                {                                                              \
                    h2v c00 = __builtin_shufflevector(t00, t00, 2*k, 2*k+1);   \
                    h2v c01 = __builtin_shufflevector(t01, t01, 2*k, 2*k+1);   \
                    h2v c10 = __builtin_shufflevector(t10, t10, 2*k, 2*k+1);   \
                    h2v c11 = __builtin_shufflevector(t11, t11, 2*k, 2*k+1);   \
                    h2v s = c11 * w11;                                         \
                    s = c10 * w10 + s;                                         \
                    s = c01 * w01 + s;                                         \
                    s = c00 * w00 + s;                                         \
                    acc = __builtin_elementwise_max(acc, s);                   \
                }
                CHUNK(0, a0) CHUNK(1, a1) CHUNK(2, a2) CHUNK(3, a3)
#undef CHUNK
            }
            float* tp = &tile[p][ch8];
            tp[0] = (float)a0[0]; tp[1] = (float)a0[1];
            tp[2] = (float)a1[0]; tp[3] = (float)a1[1];
            tp[4] = (float)a2[0]; tp[5] = (float)a2[1];
            tp[6] = (float)a3[0]; tp[7] = (float)a3[1];
        }
    }
    __syncthreads();

    // ---- phase B: float4 stores along w. unit = (c, w-quad); 2 units/thread.
#pragma unroll
    for (int rep = 0; rep < 2; ++rep) {
        const int unit = threadIdx.x + 512 * rep;   // 0..1023
        const int q = unit & 15;                    // w-quad
        const int c = unit >> 4;                    // 0..63
        const int w = w0 + 4 * q;
        if (w < WW) {
            float4 v;
            v.x = tile[4 * q + 0][c];
            v.y = tile[4 * q + 1][c];
            v.z = tile[4 * q + 2][c];
            v.w = tile[4 * q + 3][c];
            *(float4*)(out + ((size_t)bi * CC + c) * HW + h * WW + w) = v;
        }
    }
}

// ---------- fallback (round-4 kernel) if workspace is too small ----------
#define CG 16
#define NCG (CC / CG)
__global__ __launch_bounds__(256, 4) void where2comm_fuse_fallback(
    const float* __restrict__ x, const float* __restrict__ T,
    float* __restrict__ out)
{
    const int tid = blockIdx.x * blockDim.x + threadIdx.x;
    const int total = BB * NN * HW * NCG;
    if (tid >= total) return;
    const int w = tid % WW;
    int t2 = tid / WW;
    const int h = t2 % HH;
    t2 /= HH;
    const int bi = t2 % (BB * NN);
    const int cg = t2 / (BB * NN);
    const int b = bi / NN, i = bi % NN;
    const float gx = -1.0f + 2.0f * (float)w / (float)(WW - 1);
    const float gy = -1.0f + 2.0f * (float)h / (float)(HH - 1);
    float acc[CG];
#pragma unroll
    for (int c = 0; c < CG; ++c) acc[c] = -INFINITY;
    const float sHW = (float)HH / (float)WW, sWH = (float)WW / (float)HH;
    const float sW = 2.5f / (float)WW, sH = 2.5f / (float)HH;
    for (int j = 0; j < NN; ++j) {
        const float* Tm = T + ((size_t)(b * NN + i) * NN + j) * 16;
        const float m00 = Tm[0], m01 = Tm[1] * sHW, m02 = Tm[3] * sW;
        const float m10 = Tm[4] * sWH, m11 = Tm[5], m12 = Tm[7] * sH;
        const float cx = __builtin_fmaf(m00, gx, __builtin_fmaf(m01, gy, m02));
        const float cy = __builtin_fmaf(m10, gx, __builtin_fmaf(m11, gy, m12));
        const float ix = (cx + 1.0f) * (0.5f * (float)(WW - 1));
        const float iy = (cy + 1.0f) * (0.5f * (float)(HH - 1));
        const float x0f = floorf(ix), y0f = floorf(iy);
        const int x0 = (int)x0f, y0 = (int)y0f, x1 = x0 + 1, y1 = y0 + 1;
        const float wx1 = ix - x0f, wy1 = iy - y0f;
        const float wx0 = 1.0f - wx1, wy0 = 1.0f - wy1;
        const float v00 = (x0 >= 0 && x0 < WW && y0 >= 0 && y0 < HH) ? 1.0f : 0.0f;
        const float v01 = (x1 >= 0 && x1 < WW && y0 >= 0 && y0 < HH) ? 1.0f : 0.0f;
        const float v10 = (x0 >= 0 && x0 < WW && y1 >= 0 && y1 < HH) ? 1.0f : 0.0f;
        const float v11 = (x1 >= 0 && x1 < WW && y1 >= 0 && y1 < HH) ? 1.0f : 0.0f;
        const float w00 = wy0 * wx0 * v00, w01 = wy0 * wx1 * v01;
        const float w10 = wy1 * wx0 * v10, w11 = wy1 * wx1 * v11;
        const int x0c = min(max(x0, 0), WW - 1), x1c = min(max(x1, 0), WW - 1);
        const int y0c = min(max(y0, 0), HH - 1), y1c = min(max(y1, 0), HH - 1);
        const int o00 = y0c * WW + x0c, o01 = y0c * WW + x1c;
        const int o10 = y1c * WW + x0c, o11 = y1c * WW + x1c;
        const float* p = x + ((size_t)(b * NN + j) * CC + cg * CG) * HW;
        float t00[CG], t01[CG], t10[CG], t11[CG];
#pragma unroll
        for (int c = 0; c < CG; ++c) {
            const float* pc = p + (size_t)c * HW;
            t00[c] = pc[o00]; t01[c] = pc[o01]; t10[c] = pc[o10]; t11[c] = pc[o11];
        }
#pragma unroll
        for (int c = 0; c < CG; ++c) {
            const float s = __builtin_fmaf(w00, t00[c], __builtin_fmaf(w01, t01[c],
                            __builtin_fmaf(w10, t10[c], w11 * t11[c])));
            acc[c] = fmaxf(acc[c], s);
        }
    }
    float* op = out + ((size_t)bi * CC + cg * CG) * HW + h * WW + w;
#pragma unroll
    for (int c = 0; c < CG; ++c) op[(size_t)c * HW] = acc[c];
}

extern "C" void kernel_launch(void* const* d_in, const int* in_sizes, int n_in,
                              void* d_out, int out_size, void* d_ws, size_t ws_size,
                              hipStream_t stream) {
    const float* x = (const float*)d_in[0];
    const float* T = (const float*)d_in[3];
    float* out = (float*)d_out;

    if (ws_size >= PAD_B + XT_BYTES + PAD_A) {
        _Float16* xt = (_Float16*)((char*)d_ws + PAD_B);
        const int grid1 = BB * NN * HH * NTW;   // 8000
        transpose_chw_hwc<<<grid1, 256, 0, stream>>>(x, xt, (char*)d_ws);
        const int grid2 = BB * NN * HH * NTW;   // 8000
        fuse_gather<<<grid2, 512, 0, stream>>>(xt, T, out);
    } else {
        const int total = BB * NN * HW * NCG;
        where2comm_fuse_fallback<<<(total + 255) / 256, 256, 0, stream>>>(x, T, out);
    }
}